// Round 9
// baseline (292.253 us; speedup 1.0000x reference)
//
#include <hip/hip_runtime.h>

#define ACT_NONE 0
#define ACT_ELU  1
#define ACT_RELU 2
#define ACT_TANH 3

typedef __attribute__((ext_vector_type(8))) short short8;
typedef __attribute__((ext_vector_type(4))) float f32x4;

__device__ __forceinline__ float frcp(float x) { return __builtin_amdgcn_rcpf(x); }
__device__ __forceinline__ float fexp(float x) { return __expf(x); }
// safe fast tanh: 1 - 2/(e^2x + 1). x=+inf -> 1, x=-inf -> -1, no NaN.
__device__ __forceinline__ float ftanh(float x) {
    return 1.f - 2.f * frcp(fexp(2.f * x) + 1.f);
}
__device__ __forceinline__ float fsigmoid(float x) {
    return frcp(1.f + fexp(-x));
}

__device__ __forceinline__ float apply_act(float v, int act) {
    if (act == ACT_ELU)  return v > 0.f ? v : fexp(v) - 1.f;
    if (act == ACT_RELU) return fmaxf(v, 0.f);
    if (act == ACT_TANH) return ftanh(v);
    return v;
}

__device__ __forceinline__ unsigned short f2bf(float f) {
    unsigned int u = __float_as_uint(f);
    unsigned int r = (u + 0x7fffu + ((u >> 16) & 1u)) >> 16;
    return (unsigned short)r;
}
__device__ __forceinline__ float bf2f(unsigned short u) {
    return __uint_as_float(((unsigned int)u) << 16);
}

// XCD-aware remap, STRIPED panels: all nx n-tiles of one A row-panel land on the
// same XCD (panel fetched into one L2, reused nx times); panels striped p->p%8
// so heterogeneous segments stay load-balanced. Bijective when ny%8==0.
__device__ __forceinline__ void xcd_remap(int& bx, int& by, int nx, int ny) {
    if ((ny & 7) == 0) {
        int L = by * nx + bx;
        int xcd = L & 7, j = L >> 3;
        int q = j / nx;
        by = xcd + 8 * q;
        bx = j - q * nx;
    }
}

// ---------------- merged cast kernel ----------------
struct CTDesc { const float* in; unsigned short* out; int R, C, tcols, tile0; };
struct CMDesc { const float* in; unsigned short* out; int start4; };
struct CastArr {
    CTDesc t[8]; int nt; int T;
    CMDesc f[6]; int nf; int total4;
};

__global__ __launch_bounds__(256) void cast_all_kernel(CastArr a) {
    int b = blockIdx.x;
    if (b < a.T) {
        int s = 0;
        while (s + 1 < a.nt && b >= a.t[s + 1].tile0) ++s;
        const CTDesc d = a.t[s];
        int lt = b - d.tile0;
        int tr = lt / d.tcols, tc = lt % d.tcols;
        int r0 = tr * 32, c0 = tc * 32;
        __shared__ float tt[32][33];
        int tx = threadIdx.x & 31, ty = threadIdx.x >> 5; // 32 x 8
        for (int i = ty; i < 32; i += 8) {
            int r = r0 + i, c = c0 + tx;
            tt[i][tx] = (r < d.R && c < d.C) ? d.in[(size_t)r * d.C + c] : 0.f;
        }
        __syncthreads();
        for (int i = ty; i < 32; i += 8) {
            int c = c0 + i, r = r0 + tx;
            if (c < d.C && r < d.R) d.out[(size_t)c * d.R + r] = f2bf(tt[tx][i]);
        }
    } else {
        int g4 = (b - a.T) * 256 + threadIdx.x;
        if (g4 >= a.total4) return;
        int s = 0;
        while (s + 1 < a.nf && g4 >= a.f[s + 1].start4) ++s;
        int l4 = g4 - a.f[s].start4;
        float4 v = *reinterpret_cast<const float4*>(a.f[s].in + (size_t)l4 * 4);
        ushort4 o;
        o.x = f2bf(v.x); o.y = f2bf(v.y); o.z = f2bf(v.z); o.w = f2bf(v.w);
        *reinterpret_cast<ushort4*>(a.f[s].out + (size_t)l4 * 4) = o;
    }
}

// ---------------- segmented MFMA GEMM, 64x64 tiles, reg-pipelined ----------------
struct GSeg {
    const unsigned short* A;    // [Mseg, K] bf16
    const unsigned short* Bt;   // [N, K] bf16
    const unsigned short* Bt2;  // alt weights for local rows >= m_split
    const float* bias;
    const float* bias2;
    float* C;                   // fp32 out (opt)
    unsigned short* Cbf;        // bf16 out for rows < cbf_mlimit (opt)
    unsigned short* Cbf2;       // bf16 out for rows >= cbf_mlimit (opt)
    int cbf_mlimit;
    int m_split;
    int K;
    int act;
    int mt0;
};
struct GArr { GSeg s[2]; int ns; int N; };

struct KBufs { short8 a0, a1, b0, b1; };

__global__ __launch_bounds__(256) void gemm_seg_kernel(GArr g) {
    int bx = blockIdx.x, by = blockIdx.y;
    xcd_remap(bx, by, gridDim.x, gridDim.y);
    const int mt = by;
    const int si = (g.ns > 1 && mt >= g.s[1].mt0) ? 1 : 0;
    const GSeg s = g.s[si];
    const int K = s.K, N = g.N;
    const int tid = threadIdx.x;
    const int w = tid >> 6, lane = tid & 63;
    const int wr = w >> 1, wc = w & 1;
    const int lr = lane & 15, lk = lane >> 4;
    const int bm = (mt - s.mt0) * 64, bn = bx * 64;
    const unsigned short* Bu = s.Bt;
    const float* bu = s.bias;
    if (bm >= s.m_split) { Bu = s.Bt2; bu = s.bias2; }

    const unsigned short* Ap = s.A + (size_t)(bm + wr * 32 + lr) * K + lk * 8;
    const unsigned short* Bp = Bu + (size_t)(bn + wc * 32 + lr) * K + lk * 8;
    const size_t r16A = (size_t)16 * K;

    f32x4 acc[2][2] = {};
    KBufs u0, u1, u2, u3;
    auto LD = [&](KBufs& u, int kk) {
        kk = kk < K ? kk : 0;   // tail prefetch clamp (discarded)
        u.a0 = *reinterpret_cast<const short8*>(Ap + kk);
        u.a1 = *reinterpret_cast<const short8*>(Ap + r16A + kk);
        u.b0 = *reinterpret_cast<const short8*>(Bp + kk);
        u.b1 = *reinterpret_cast<const short8*>(Bp + r16A + kk);
    };
    auto MM = [&](const KBufs& u) {
        acc[0][0] = __builtin_amdgcn_mfma_f32_16x16x32_bf16(u.a0, u.b0, acc[0][0], 0, 0, 0);
        acc[0][1] = __builtin_amdgcn_mfma_f32_16x16x32_bf16(u.a0, u.b1, acc[0][1], 0, 0, 0);
        acc[1][0] = __builtin_amdgcn_mfma_f32_16x16x32_bf16(u.a1, u.b0, acc[1][0], 0, 0, 0);
        acc[1][1] = __builtin_amdgcn_mfma_f32_16x16x32_bf16(u.a1, u.b1, acc[1][1], 0, 0, 0);
    };
    // depth-3 software pipeline, K % 128 == 0
    LD(u0, 0); LD(u1, 32); LD(u2, 64);
    for (int k = 0; k < K; k += 128) {
        LD(u3, k + 96);  MM(u0);
        LD(u0, k + 128); MM(u1);
        LD(u1, k + 160); MM(u2);
        LD(u2, k + 192); MM(u3);
    }
    #pragma unroll
    for (int i = 0; i < 2; ++i) {
        #pragma unroll
        for (int j = 0; j < 2; ++j) {
            int gcol = bn + wc * 32 + j * 16 + lr;
            float bv = bu ? bu[gcol] : 0.f;
            #pragma unroll
            for (int r = 0; r < 4; ++r) {
                int grow = bm + wr * 32 + i * 16 + lk * 4 + r;
                float v = apply_act(acc[i][j][r] + bv, s.act);
                if (s.C) s.C[(size_t)grow * N + gcol] = v;
                if (grow < s.cbf_mlimit) {
                    if (s.Cbf)  s.Cbf[(size_t)grow * N + gcol] = f2bf(v);
                } else {
                    if (s.Cbf2) s.Cbf2[(size_t)(grow - s.cbf_mlimit) * N + gcol] = f2bf(v);
                }
            }
        }
    }
}

// ---------------- split-K MFMA GEMM (fp32 partial planes), reg-pipelined ----------------
// ksplit must be a multiple of 128.
__global__ __launch_bounds__(256) void gemm_splitk_kernel(
    const unsigned short* __restrict__ A, const unsigned short* __restrict__ Bt,
    const unsigned short* __restrict__ Bt2, int m_split,
    float* __restrict__ C, int M, int K, int N, int ksplit) {
    int bx = blockIdx.x, by = blockIdx.y;
    xcd_remap(bx, by, gridDim.x, gridDim.y);
    const int tid = threadIdx.x;
    const int w = tid >> 6, lane = tid & 63;
    const int wr = w >> 1, wc = w & 1;
    const int lr = lane & 15, lk = lane >> 4;
    const int bm = by * 64, bn = bx * 64;
    const int z = blockIdx.z;
    const int kbeg = z * ksplit;
    const int kend = kbeg + ksplit < K ? kbeg + ksplit : K;
    const int KL = kend - kbeg;
    C += (size_t)z * M * N;
    const unsigned short* Bu = (bm >= m_split) ? Bt2 : Bt;

    const unsigned short* Ap = A + (size_t)(bm + wr * 32 + lr) * K + kbeg + lk * 8;
    const unsigned short* Bp = Bu + (size_t)(bn + wc * 32 + lr) * K + kbeg + lk * 8;
    const size_t r16 = (size_t)16 * K;

    f32x4 acc[2][2] = {};
    KBufs u0, u1, u2, u3;
    auto LD = [&](KBufs& u, int kk) {
        kk = kk < KL ? kk : 0;
        u.a0 = *reinterpret_cast<const short8*>(Ap + kk);
        u.a1 = *reinterpret_cast<const short8*>(Ap + r16 + kk);
        u.b0 = *reinterpret_cast<const short8*>(Bp + kk);
        u.b1 = *reinterpret_cast<const short8*>(Bp + r16 + kk);
    };
    auto MM = [&](const KBufs& u) {
        acc[0][0] = __builtin_amdgcn_mfma_f32_16x16x32_bf16(u.a0, u.b0, acc[0][0], 0, 0, 0);
        acc[0][1] = __builtin_amdgcn_mfma_f32_16x16x32_bf16(u.a0, u.b1, acc[0][1], 0, 0, 0);
        acc[1][0] = __builtin_amdgcn_mfma_f32_16x16x32_bf16(u.a1, u.b0, acc[1][0], 0, 0, 0);
        acc[1][1] = __builtin_amdgcn_mfma_f32_16x16x32_bf16(u.a1, u.b1, acc[1][1], 0, 0, 0);
    };
    LD(u0, 0); LD(u1, 32); LD(u2, 64);
    for (int k = 0; k < KL; k += 128) {
        LD(u3, k + 96);  MM(u0);
        LD(u0, k + 128); MM(u1);
        LD(u1, k + 160); MM(u2);
        LD(u2, k + 192); MM(u3);
    }
    #pragma unroll
    for (int i = 0; i < 2; ++i)
        #pragma unroll
        for (int j = 0; j < 2; ++j) {
            int gcol = bn + wc * 32 + j * 16 + lr;
            #pragma unroll
            for (int r = 0; r < 4; ++r) {
                int grow = bm + wr * 32 + i * 16 + lk * 4 + r;
                C[(size_t)grow * N + gcol] = acc[i][j][r];
            }
        }
}

// ---------------- sparse ops ----------------
__global__ __launch_bounds__(256) void neiagg_kernel(
    const float* __restrict__ nei0, const float* __restrict__ nei1,
    const unsigned short* __restrict__ hn0, const unsigned short* __restrict__ hn1,
    unsigned short* __restrict__ hagg) {
    const int row = blockIdx.x, br = blockIdx.y, t = threadIdx.x;
    const float* nei = br ? nei1 : nei0;
    const unsigned short* hn = br ? hn1 : hn0;
    __shared__ int idxs[256];
    __shared__ int cnt;
    if (t == 0) cnt = 0;
    __syncthreads();
    const float4* nr = reinterpret_cast<const float4*>(nei + (size_t)row * 4096);
    for (int j = t; j < 1024; j += 256) {
        float4 v = nr[j];
        if (v.x != 0.f) { int s = atomicAdd(&cnt, 1); if (s < 256) idxs[s] = j * 4 + 0; }
        if (v.y != 0.f) { int s = atomicAdd(&cnt, 1); if (s < 256) idxs[s] = j * 4 + 1; }
        if (v.z != 0.f) { int s = atomicAdd(&cnt, 1); if (s < 256) idxs[s] = j * 4 + 2; }
        if (v.w != 0.f) { int s = atomicAdd(&cnt, 1); if (s < 256) idxs[s] = j * 4 + 3; }
    }
    __syncthreads();
    int n = cnt < 256 ? cnt : 256;
    float inv = frcp(fmaxf((float)cnt, 1.f));
    int c = t * 2;
    float a0 = 0.f, a1 = 0.f, b0 = 0.f, b1 = 0.f;
    int k = 0;
    for (; k + 2 <= n; k += 2) {
        ushort2 u = *reinterpret_cast<const ushort2*>(&hn[(size_t)idxs[k] * 512 + c]);
        ushort2 v = *reinterpret_cast<const ushort2*>(&hn[(size_t)idxs[k + 1] * 512 + c]);
        a0 += bf2f(u.x); a1 += bf2f(u.y);
        b0 += bf2f(v.x); b1 += bf2f(v.y);
    }
    if (k < n) {
        ushort2 u = *reinterpret_cast<const ushort2*>(&hn[(size_t)idxs[k] * 512 + c]);
        a0 += bf2f(u.x); a1 += bf2f(u.y);
    }
    ushort2 o; o.x = f2bf((a0 + b0) * inv); o.y = f2bf((a1 + b1) * inv);
    *reinterpret_cast<ushort2*>(&hagg[((size_t)br * 1024 + row) * 512 + c]) = o;
}

// views/masks; h_tar/h_mask now bf16; tbuf has 2 split-K planes (stride PL)
__global__ void addelu_kernel(const unsigned short* __restrict__ ht,
                              const unsigned short* __restrict__ hm,
                              const float* __restrict__ tt, unsigned short* __restrict__ xcat,
                              int nh, int PL) {
    int idx = blockIdx.x * 256 + threadIdx.x;
    if (idx < nh) {
        float h1 = bf2f(ht[idx]), h2 = bf2f(hm[idx]);
        float t0 = tt[idx] + tt[idx + PL];
        float t1 = tt[idx + nh] + tt[idx + nh + PL];
        float a = h1 + t0, b = h2 + t0, c = h1 + t1, d = h2 + t1;
        xcat[(size_t)1 * nh + idx] = f2bf(a > 0.f ? a : fexp(a) - 1.f);
        xcat[(size_t)2 * nh + idx] = f2bf(b > 0.f ? b : fexp(b) - 1.f);
        xcat[(size_t)3 * nh + idx] = f2bf(c > 0.f ? c : fexp(c) - 1.f);
        xcat[(size_t)4 * nh + idx] = f2bf(d > 0.f ? d : fexp(d) - 1.f);
    }
}

// scan adjacency rows once. br0 = 0.5*(adj0+adj1), 1=adj0, 2=madj0, 3=adj1, 4=madj1
__global__ __launch_bounds__(64) void adjprep_kernel(
    const float* __restrict__ adj0, const float* __restrict__ adj1,
    const float* __restrict__ madj0, const float* __restrict__ madj1,
    int* __restrict__ cnts, int* __restrict__ idxs, float* __restrict__ wts) {
    const int row = blockIdx.x, br = blockIdx.y, t = threadIdx.x;
    const float* Aa; const float* Ab = nullptr; float sc = 1.f;
    if (br == 0)      { Aa = adj0; Ab = adj1; sc = 0.5f; }
    else if (br == 1) { Aa = adj0; }
    else if (br == 2) { Aa = madj0; }
    else if (br == 3) { Aa = adj1; }
    else              { Aa = madj1; }
    __shared__ int li[128];
    __shared__ float lw[128];
    __shared__ int cnt;
    if (t == 0) cnt = 0;
    __syncthreads();
    const float4* ar = reinterpret_cast<const float4*>(Aa + (size_t)row * 1024);
    const float4* brp = Ab ? reinterpret_cast<const float4*>(Ab + (size_t)row * 1024) : nullptr;
    for (int j = t; j < 256; j += 64) {
        float4 v = ar[j];
        if (brp) { float4 u = brp[j]; v.x += u.x; v.y += u.y; v.z += u.z; v.w += u.w; }
        if (v.x != 0.f) { int s = atomicAdd(&cnt, 1); if (s < 128) { li[s] = j * 4 + 0; lw[s] = v.x * sc; } }
        if (v.y != 0.f) { int s = atomicAdd(&cnt, 1); if (s < 128) { li[s] = j * 4 + 1; lw[s] = v.y * sc; } }
        if (v.z != 0.f) { int s = atomicAdd(&cnt, 1); if (s < 128) { li[s] = j * 4 + 2; lw[s] = v.z * sc; } }
        if (v.w != 0.f) { int s = atomicAdd(&cnt, 1); if (s < 128) { li[s] = j * 4 + 3; lw[s] = v.w * sc; } }
    }
    __syncthreads();
    int n = cnt < 128 ? cnt : 128;
    size_t base = ((size_t)br * 1024 + row) * 128;
    for (int k = t; k < n; k += 64) { idxs[base + k] = li[k]; wts[base + k] = lw[k]; }
    if (t == 0) cnts[br * 1024 + row] = n;
}

// h1cat[br] = bf16(relu(adj_br @ (X0+X1)[br] + b1)); X has 2 split-K planes stride PL
__global__ __launch_bounds__(256) void spmm1_kernel(
    const int* __restrict__ cnts, const int* __restrict__ idxs, const float* __restrict__ wts,
    const float* __restrict__ X, int PL, const float* __restrict__ bias,
    unsigned short* __restrict__ out) {
    const int row = blockIdx.x * 4 + (threadIdx.x >> 6);
    const int br = blockIdx.y, t = threadIdx.x & 63;
    size_t base = ((size_t)br * 1024 + row) * 128;
    int n = cnts[br * 1024 + row];
    const float* Xb = X + (size_t)br * 1024 * 64;
    const float* Xb2 = Xb + PL;
    float acc = bias[t], a1 = 0.f;
    int k = 0;
    for (; k + 2 <= n; k += 2) {
        int   i0 = idxs[base + k], i1 = idxs[base + k + 1];
        float w0 = wts[base + k],  w1 = wts[base + k + 1];
        acc += w0 * (Xb[(size_t)i0 * 64 + t] + Xb2[(size_t)i0 * 64 + t]);
        a1  += w1 * (Xb[(size_t)i1 * 64 + t] + Xb2[(size_t)i1 * 64 + t]);
    }
    if (k < n) {
        int i0 = idxs[base + k];
        acc += wts[base + k] * (Xb[(size_t)i0 * 64 + t] + Xb2[(size_t)i0 * 64 + t]);
    }
    acc += a1;
    out[((size_t)br * 1024 + row) * 64 + t] = f2bf(fmaxf(acc, 0.f));
}

// Fused: g = adj_br @ h1 (gather bf16), o = g @ w2 + b2; br0 -> zcf_bf;
// br1..4 -> l2norm(o) -> hs + att row value.
__global__ __launch_bounds__(256) void spmm2_kernel(
    const int* __restrict__ cnts, const int* __restrict__ idxs, const float* __restrict__ wts,
    const unsigned short* __restrict__ H1, const float* __restrict__ w2,
    const float* __restrict__ b2, unsigned short* __restrict__ zcf_bf,
    float* __restrict__ hs, const float* __restrict__ att_w,
    const float* __restrict__ att_b, const float* __restrict__ att_vec,
    float* __restrict__ att_row) {
    const int wv = threadIdx.x >> 6;
    const int row = blockIdx.x * 4 + wv;
    const int br = blockIdx.y, t = threadIdx.x & 63;
    size_t base = ((size_t)br * 1024 + row) * 128;
    int n = cnts[br * 1024 + row];
    const unsigned short* Hb = H1 + (size_t)br * 1024 * 64;
    float g0 = 0.f, g1 = 0.f, g2 = 0.f, g3 = 0.f;
    int k = 0;
    for (; k + 4 <= n; k += 4) {
        g0 += wts[base + k]     * bf2f(Hb[(size_t)idxs[base + k]     * 64 + t]);
        g1 += wts[base + k + 1] * bf2f(Hb[(size_t)idxs[base + k + 1] * 64 + t]);
        g2 += wts[base + k + 2] * bf2f(Hb[(size_t)idxs[base + k + 2] * 64 + t]);
        g3 += wts[base + k + 3] * bf2f(Hb[(size_t)idxs[base + k + 3] * 64 + t]);
    }
    for (; k < n; ++k) g0 += wts[base + k] * bf2f(Hb[(size_t)idxs[base + k] * 64 + t]);
    float g = (g0 + g1) + (g2 + g3);
    __shared__ float rs[4][64];
    rs[wv][t] = g;   // same-wave write/read: lockstep, no barrier
    float o = b2[t];
    #pragma unroll
    for (int c = 0; c < 64; ++c) o += rs[wv][c] * w2[c * 64 + t];
    if (br == 0) {
        zcf_bf[(size_t)row * 64 + t] = f2bf(o);
        return;
    }
    float s = o * o;
    #pragma unroll
    for (int q = 32; q; q >>= 1) s += __shfl_down(s, q);
    s = __shfl(s, 0);
    float v = o * frcp(fmaxf(sqrtf(s), 1e-12f));
    hs[((size_t)(br - 1) * 1024 + row) * 64 + t] = v;
    rs[wv][t] = v;   // safe overwrite (wave-sync)
    float sa = att_b[t];
    #pragma unroll
    for (int c = 0; c < 64; ++c) sa += rs[wv][c] * att_w[c * 64 + t];
    float val = ftanh(sa) * att_vec[t];
    #pragma unroll
    for (int q = 32; q; q >>= 1) val += __shfl_down(val, q);
    if (t == 0) att_row[(size_t)(br - 1) * 1024 + row] = val;
}

__global__ __launch_bounds__(256) void attreduce_kernel(const float* __restrict__ att_row,
                                                        float* __restrict__ small) {
    const int v = blockIdx.x, t = threadIdx.x;
    const float* p = att_row + (size_t)v * 1024;
    float s = p[t] + p[t + 256] + p[t + 512] + p[t + 768];
    #pragma unroll
    for (int o = 32; o; o >>= 1) s += __shfl_down(s, o);
    __shared__ float ps[4];
    if ((t & 63) == 0) ps[t >> 6] = s;
    __syncthreads();
    if (t == 0) small[v] = ps[0] + ps[1] + ps[2] + ps[3];
}

// Fused projection head: rows [0,N) z_coarse (from zcf_bf), rows [N,2N) z_fine
__global__ __launch_bounds__(256) void projhead_kernel(
    const unsigned short* __restrict__ zcf_bf, const float* __restrict__ hs,
    const float* __restrict__ small, const float* __restrict__ proj_w,
    const float* __restrict__ proj_b, const float* __restrict__ mlp1_w,
    float* __restrict__ zcat, float* __restrict__ AC1) {
    const int wv = threadIdx.x >> 6;
    const int row = blockIdx.x * 4 + wv;
    const int t = threadIdx.x & 63;
    float zv;
    if (row < 1024) {
        zv = bf2f(zcf_bf[(size_t)row * 64 + t]);
    } else {
        int r = row - 1024;
        float e0 = small[0] * (1.f / 1024.f), e1 = small[1] * (1.f / 1024.f);
        float e2 = small[2] * (1.f / 1024.f), e3 = small[3] * (1.f / 1024.f);
        float mx = fmaxf(fmaxf(e0, e1), fmaxf(e2, e3));
        float x0 = expf(e0 - mx), x1 = expf(e1 - mx), x2 = expf(e2 - mx), x3 = expf(e3 - mx);
        float inv = 1.f / (x0 + x1 + x2 + x3);
        size_t ix = (size_t)r * 64 + t;
        zv = (x0 * hs[ix] + x1 * hs[ix + 65536] +
              x2 * hs[ix + 131072] + x3 * hs[ix + 196608]) * inv;
    }
    __shared__ float rs[4][64];
    rs[wv][t] = zv;
    float p = proj_b[t];
    #pragma unroll
    for (int c = 0; c < 64; ++c) p += rs[wv][c] * proj_w[c * 64 + t];
    p = ftanh(p);
    float s = p * p;
    #pragma unroll
    for (int q = 32; q; q >>= 1) s += __shfl_down(s, q);
    s = __shfl(s, 0);
    float r = p * frcp(fmaxf(sqrtf(s), 1e-12f));
    zcat[(size_t)row * 64 + t] = r;
    rs[wv][t] = r;
    if (t < 16) {
        float a = 0.f;
        #pragma unroll
        for (int c = 0; c < 64; ++c) a += rs[wv][c] * mlp1_w[c * 16 + t];
        AC1[(size_t)row * 16 + t] = a;
    }
}

// 4 anchors per block
__global__ __launch_bounds__(256) void infonce_kernel(
    const float* __restrict__ zf, const float* __restrict__ zc,
    const float* __restrict__ A1, const float* __restrict__ C1,
    const float* __restrict__ b1, const float* __restrict__ m2,
    const float* __restrict__ b2v, float* __restrict__ loss_acc) {
    const int i0 = blockIdx.x * 4, t = threadIdx.x;
    __shared__ __align__(16) float zfs[4][64];
    __shared__ float a1b[4][16], m2s[16];
    __shared__ float diag[4];
    __shared__ float wsum[4][4];
    if (t < 64) {
        #pragma unroll
        for (int ii = 0; ii < 4; ++ii) zfs[ii][t] = zf[(size_t)(i0 + ii) * 64 + t];
    }
    if (t < 16) {
        float bb = b1[t];
        #pragma unroll
        for (int ii = 0; ii < 4; ++ii) a1b[ii][t] = A1[(size_t)(i0 + ii) * 16 + t] + bb;
        m2s[t] = m2[t];
    }
    __syncthreads();
    const float b2 = b2v[0];
    float acc[4] = {};
    for (int j = t; j < 1024; j += 256) {
        const float4* zcj = reinterpret_cast<const float4*>(zc + (size_t)j * 64);
        float dot[4] = {};
        #pragma unroll
        for (int e = 0; e < 16; ++e) {
            float4 b = zcj[e];
            #pragma unroll
            for (int ii = 0; ii < 4; ++ii) {
                float4 a = reinterpret_cast<const float4*>(zfs[ii])[e];
                dot[ii] += a.x * b.x + a.y * b.y + a.z * b.z + a.w * b.w;
            }
        }
        float c1j[16];
        #pragma unroll
        for (int q = 0; q < 4; ++q) {
            float4 c4 = reinterpret_cast<const float4*>(C1 + (size_t)j * 16)[q];
            c1j[q * 4 + 0] = c4.x; c1j[q * 4 + 1] = c4.y;
            c1j[q * 4 + 2] = c4.z; c1j[q * 4 + 3] = c4.w;
        }
        #pragma unroll
        for (int ii = 0; ii < 4; ++ii) {
            float logit = dot[ii] * 2.0f; // 1/TAU
            float h = b2;
            #pragma unroll
            for (int k = 0; k < 16; ++k) h += ftanh(a1b[ii][k] + c1j[k]) * m2s[k];
            acc[ii] += fexp(logit) * fsigmoid(h);
            if (j == i0 + ii) diag[ii] = logit;
        }
    }
    #pragma unroll
    for (int ii = 0; ii < 4; ++ii) {
        float a = acc[ii];
        #pragma unroll
        for (int o = 32; o; o >>= 1) a += __shfl_down(a, o);
        if ((t & 63) == 0) wsum[t >> 6][ii] = a;
    }
    __syncthreads();
    if (t == 0) {
        float part = 0.f;
        #pragma unroll
        for (int ii = 0; ii < 4; ++ii) {
            float denom = wsum[0][ii] + wsum[1][ii] + wsum[2][ii] + wsum[3][ii];
            part += logf(denom) - diag[ii];
        }
        atomicAdd(loss_acc, part);
    }
}

__global__ void finalize_kernel(const float* __restrict__ small, float* __restrict__ out) {
    if (threadIdx.x == 0) out[0] = small[4] * (1.f / 1024.f);
}

extern "C" void kernel_launch(void* const* d_in, const int* in_sizes, int n_in,
                              void* d_out, int out_size, void* d_ws, size_t ws_size,
                              hipStream_t stream) {
    const float* feat0     = (const float*)d_in[0];
    const float* feat1     = (const float*)d_in[1];
    const float* feat2     = (const float*)d_in[2];
    const float* mask_feat = (const float*)d_in[3];
    const float* nei0      = (const float*)d_in[4];
    const float* nei1      = (const float*)d_in[5];
    const float* adj0      = (const float*)d_in[6];
    const float* adj1      = (const float*)d_in[7];
    const float* madj0     = (const float*)d_in[8];
    const float* madj1     = (const float*)d_in[9];
    const float* fc0_w = (const float*)d_in[10];
    const float* fc0_b = (const float*)d_in[11];
    const float* fc1_w = (const float*)d_in[12];
    const float* fc1_b = (const float*)d_in[13];
    const float* fc2_w = (const float*)d_in[14];
    const float* fc2_b = (const float*)d_in[15];
    const float* agg0_w = (const float*)d_in[16];
    const float* agg1_w = (const float*)d_in[17];
    const float* gcn_w1 = (const float*)d_in[18];
    const float* gcn_b1 = (const float*)d_in[19];
    const float* gcn_w2 = (const float*)d_in[20];
    const float* gcn_b2 = (const float*)d_in[21];
    const float* att_w  = (const float*)d_in[22];
    const float* att_b  = (const float*)d_in[23];
    const float* att_vec = (const float*)d_in[24];
    const float* proj_w = (const float*)d_in[25];
    const float* proj_b = (const float*)d_in[26];
    const float* mlp1_w = (const float*)d_in[27];
    const float* mlp1_b = (const float*)d_in[28];
    const float* mlp2_w = (const float*)d_in[29];
    const float* mlp2_b = (const float*)d_in[30];

    const int N = 1024, M = 4096, D0 = 1024, D1 = 512, H = 512, E = 64;
    typedef unsigned short bf;

    // ---- workspace ----
    float* W = (float*)d_ws;
    size_t off = 0;
    auto allocf = [&](size_t n) { float* p = W + off; off += n; return p; };
    float* tbuf    = allocf((size_t)2 * 2 * N * H); // 2 split-K planes
    float* xw1cat  = allocf((size_t)2 * 5 * N * E); // 2 split-K planes
    float* hs      = allocf((size_t)4 * N * E);
    float* zcat    = allocf((size_t)2 * N * E);
    float* AC1     = allocf((size_t)2 * N * 16);
    float* att_row = allocf((size_t)4 * N);
    float* small   = allocf(16);
    float* adj_wts = allocf((size_t)5 * 1024 * 128);
    int*   adj_idx = (int*)allocf((size_t)5 * 1024 * 128);
    int*   adj_cnt = (int*)allocf((size_t)5 * 1024);
    bf* BP = (bf*)(W + off);
    size_t boff = 0;
    auto allocb = [&](size_t n) { bf* p = BP + boff; boff += n; return p; };
    bf* feat0_bf = allocb((size_t)N * D0);   // feat0 | mask contiguous
    bf* mask_bf  = allocb((size_t)N * D0);
    bf* feat1_bf = allocb((size_t)M * D1);   // feat1 | feat2 contiguous
    bf* feat2_bf = allocb((size_t)M * D1);
    bf* xcat_bf  = allocb((size_t)5 * N * H); // branch0 = h_tar bf16
    bf* hmask_bf = allocb((size_t)N * H);
    bf* hnei0_bf = allocb((size_t)M * H);    // hnei0 | hnei1 contiguous
    bf* hnei1_bf = allocb((size_t)M * H);
    bf* hagg_bf  = allocb((size_t)2 * N * H);
    bf* h1cat_bf = allocb((size_t)5 * N * E);
    bf* zcf_bf   = allocb((size_t)N * E);
    bf* fc0_wT  = allocb((size_t)H * D0);
    bf* fc1_wT  = allocb((size_t)H * D1);
    bf* fc2_wT  = allocb((size_t)H * D1);
    bf* agg0_wT = allocb((size_t)H * H);
    bf* agg1_wT = allocb((size_t)H * H);
    bf* gw1_T   = allocb((size_t)E * H);

    hipMemsetAsync((void*)small, 0, 16 * sizeof(float), stream);

    // single merged cast launch: 6 weight transposes + 4 flat input casts
    {
        CastArr a; int tile = 0, i = 0;
        auto addT = [&](const float* in, bf* out, int R, int C) {
            int tc = (C + 31) / 32, trn = (R + 31) / 32;
            a.t[i++] = CTDesc{in, out, R, C, tc, tile};
            tile += tc * trn;
        };
        addT(fc0_w, fc0_wT, D0, H);
        addT(fc1_w, fc1_wT, D1, H);
        addT(fc2_w, fc2_wT, D1, H);
        addT(agg0_w, agg0_wT, H, H);
        addT(agg1_w, agg1_wT, H, H);
        addT(gcn_w1, gw1_T, H, E);
        a.nt = i; a.T = tile;
        int s4 = 0, fi = 0;
        auto addF = [&](const float* in, bf* out, int n) {
            a.f[fi++] = CMDesc{in, out, s4}; s4 += n / 4;
        };
        addF(feat0, feat0_bf, N * D0);
        addF(mask_feat, mask_bf, N * D0);
        addF(feat1, feat1_bf, M * D1);
        addF(feat2, feat2_bf, M * D1);
        a.nf = fi; a.total4 = s4;
        int nb = tile + (s4 + 255) / 256;
        cast_all_kernel<<<nb, 256, 0, stream>>>(a);
    }
    // adjacency -> compact lists
    adjprep_kernel<<<dim3(N, 5), 64, 0, stream>>>(adj0, adj1, madj0, madj1,
                                                  adj_cnt, adj_idx, adj_wts);

    // merged projections GEMM: seg0 [feat0;mask]@fc0 -> bf16 [xcat0 | hmask],
    // seg1 [feat1;feat2]@fc1/fc2 -> bf16 hnei. 1280 blocks, XCD-striped.
    {
        GArr g;
        g.s[0] = GSeg{feat0_bf, fc0_wT, nullptr, fc0_b, nullptr,
                      nullptr, xcat_bf, hmask_bf, N, 1 << 30, D0, ACT_ELU, 0};
        g.s[1] = GSeg{feat1_bf, fc1_wT, fc2_wT, fc1_b, fc2_b,
                      nullptr, hnei0_bf, nullptr, 2 * M, M, D1, ACT_ELU, 32};
        g.ns = 2; g.N = H;
        gemm_seg_kernel<<<dim3(H / 64, 32 + 128), 256, 0, stream>>>(g);
    }

    // meta-path aggregation
    neiagg_kernel<<<dim3(N, 2), 256, 0, stream>>>(nei0, nei1, hnei0_bf, hnei1_bf, hagg_bf);
    // agg GEMM split-K x2: [hagg0;hagg1]@agg0/agg1 -> 2 fp32 planes in tbuf
    gemm_splitk_kernel<<<dim3(H / 64, 2 * N / 64, 2), 256, 0, stream>>>(
        hagg_bf, agg0_wT, agg1_wT, N, tbuf, 2 * N, H, H, 256);
    addelu_kernel<<<(N * H + 255) / 256, 256, 0, stream>>>(xcat_bf, hmask_bf, tbuf, xcat_bf,
                                                           N * H, 2 * N * H);

    // GCN layer 1: xcat@gw1 split-K x2 -> 2 planes, then spmm1 (sums planes)
    gemm_splitk_kernel<<<dim3(1, 5 * N / 64, 2), 256, 0, stream>>>(
        xcat_bf, gw1_T, nullptr, 1 << 30, xw1cat, 5 * N, H, E, 256);
    spmm1_kernel<<<dim3(N / 4, 5), 256, 0, stream>>>(adj_cnt, adj_idx, adj_wts,
                                                     xw1cat, 5 * N * E, gcn_b1, h1cat_bf);
    // GCN layer 2 fused: spmm2 = gather(h1) @ w2 + b2 (+l2norm +att)
    spmm2_kernel<<<dim3(N / 4, 5), 256, 0, stream>>>(adj_cnt, adj_idx, adj_wts, h1cat_bf,
                                                     gcn_w2, gcn_b2, zcf_bf, hs,
                                                     att_w, att_b, att_vec, att_row);
    attreduce_kernel<<<4, 256, 0, stream>>>(att_row, small);

    // fused zfine + projection + l2norm + mlp1 matvec
    projhead_kernel<<<2 * N / 4, 256, 0, stream>>>(zcf_bf, hs, small, proj_w, proj_b,
                                                   mlp1_w, zcat, AC1);

    // InfoNCE
    const float* zc = zcat;
    const float* zf = zcat + (size_t)N * E;
    const float* C1 = AC1;
    const float* A1 = AC1 + (size_t)N * 16;
    infonce_kernel<<<N / 4, 256, 0, stream>>>(zf, zc, A1, C1, mlp1_b, mlp2_w, mlp2_b, small + 4);

    finalize_kernel<<<1, 64, 0, stream>>>(small, (float*)d_out);
}

// Round 10
// 282.927 us; speedup vs baseline: 1.0330x; 1.0330x over previous
//
#include <hip/hip_runtime.h>

#define ACT_NONE 0
#define ACT_ELU  1
#define ACT_RELU 2
#define ACT_TANH 3

typedef __attribute__((ext_vector_type(8))) short short8;
typedef __attribute__((ext_vector_type(4))) float f32x4;

__device__ __forceinline__ float frcp(float x) { return __builtin_amdgcn_rcpf(x); }
__device__ __forceinline__ float fexp(float x) { return __expf(x); }
// safe fast tanh: 1 - 2/(e^2x + 1). x=+inf -> 1, x=-inf -> -1, no NaN.
__device__ __forceinline__ float ftanh(float x) {
    return 1.f - 2.f * frcp(fexp(2.f * x) + 1.f);
}
__device__ __forceinline__ float fsigmoid(float x) {
    return frcp(1.f + fexp(-x));
}

__device__ __forceinline__ float apply_act(float v, int act) {
    if (act == ACT_ELU)  return v > 0.f ? v : fexp(v) - 1.f;
    if (act == ACT_RELU) return fmaxf(v, 0.f);
    if (act == ACT_TANH) return ftanh(v);
    return v;
}

__device__ __forceinline__ unsigned short f2bf(float f) {
    unsigned int u = __float_as_uint(f);
    unsigned int r = (u + 0x7fffu + ((u >> 16) & 1u)) >> 16;
    return (unsigned short)r;
}
__device__ __forceinline__ float bf2f(unsigned short u) {
    return __uint_as_float(((unsigned int)u) << 16);
}

#define GLOAD16(gp, lp) __builtin_amdgcn_global_load_lds( \
    (const __attribute__((address_space(1))) void*)(gp),  \
    (__attribute__((address_space(3))) void*)(lp), 16, 0, 0)

// XCD-aware remap, STRIPED panels: all nx n-tiles of one A row-panel land on
// the same XCD (panel fetched into one L2, reused nx times); panels striped
// p->p%8 so heterogeneous segments stay balanced. Bijective when ny%8==0.
__device__ __forceinline__ void xcd_remap(int& bx, int& by, int nx, int ny) {
    if ((ny & 7) == 0) {
        int L = by * nx + bx;
        int xcd = L & 7, j = L >> 3;
        int q = j / nx;
        by = xcd + 8 * q;
        bx = j - q * nx;
    }
}

// ---------------- merged prep kernel: weight transposes + input casts + adjprep ----
struct CTDesc { const float* in; unsigned short* out; int R, C, tcols, tile0; };
struct CMDesc { const float* in; unsigned short* out; int start4; };
struct CastArr {
    CTDesc t[8]; int nt; int T;
    CMDesc f[6]; int nf; int total4; int F;
    // adjprep
    const float* adj0; const float* adj1; const float* madj0; const float* madj1;
    int* cnts; int* idxs; float* wts;
};

__global__ __launch_bounds__(256) void cast_all_kernel(CastArr a) {
    int b = blockIdx.x;
    __shared__ float tt[32][33];
    __shared__ int li[4][128];
    __shared__ float lw[4][128];
    __shared__ int cnt[4];
    if (b < a.T) {
        int s = 0;
        while (s + 1 < a.nt && b >= a.t[s + 1].tile0) ++s;
        const CTDesc d = a.t[s];
        int lt = b - d.tile0;
        int tr = lt / d.tcols, tc = lt % d.tcols;
        int r0 = tr * 32, c0 = tc * 32;
        int tx = threadIdx.x & 31, ty = threadIdx.x >> 5; // 32 x 8
        for (int i = ty; i < 32; i += 8) {
            int r = r0 + i, c = c0 + tx;
            tt[i][tx] = (r < d.R && c < d.C) ? d.in[(size_t)r * d.C + c] : 0.f;
        }
        __syncthreads();
        for (int i = ty; i < 32; i += 8) {
            int c = c0 + i, r = r0 + tx;
            if (c < d.C && r < d.R) d.out[(size_t)c * d.R + r] = f2bf(tt[tx][i]);
        }
    } else if (b < a.T + a.F) {
        int g4 = (b - a.T) * 256 + threadIdx.x;
        if (g4 >= a.total4) return;
        int s = 0;
        while (s + 1 < a.nf && g4 >= a.f[s + 1].start4) ++s;
        int l4 = g4 - a.f[s].start4;
        float4 v = *reinterpret_cast<const float4*>(a.f[s].in + (size_t)l4 * 4);
        ushort4 o;
        o.x = f2bf(v.x); o.y = f2bf(v.y); o.z = f2bf(v.z); o.w = f2bf(v.w);
        *reinterpret_cast<ushort4*>(a.f[s].out + (size_t)l4 * 4) = o;
    } else {
        // adjprep: one wave per (row, br) pair. br0=0.5*(adj0+adj1),1=adj0,2=madj0,3=adj1,4=madj1
        int wv = threadIdx.x >> 6, t = threadIdx.x & 63;
        int p = (b - a.T - a.F) * 4 + wv;     // 0..5119
        int row = p & 1023, br = p >> 10;
        const float* Aa; const float* Ab = nullptr; float sc = 1.f;
        if (br == 0)      { Aa = a.adj0; Ab = a.adj1; sc = 0.5f; }
        else if (br == 1) { Aa = a.adj0; }
        else if (br == 2) { Aa = a.madj0; }
        else if (br == 3) { Aa = a.adj1; }
        else              { Aa = a.madj1; }
        if (t == 0) cnt[wv] = 0;
        // wave-private shared: lockstep within wave, no barrier needed
        const float4* ar = reinterpret_cast<const float4*>(Aa + (size_t)row * 1024);
        const float4* brp = Ab ? reinterpret_cast<const float4*>(Ab + (size_t)row * 1024) : nullptr;
        for (int j = t; j < 256; j += 64) {
            float4 v = ar[j];
            if (brp) { float4 u = brp[j]; v.x += u.x; v.y += u.y; v.z += u.z; v.w += u.w; }
            if (v.x != 0.f) { int s = atomicAdd(&cnt[wv], 1); if (s < 128) { li[wv][s] = j * 4 + 0; lw[wv][s] = v.x * sc; } }
            if (v.y != 0.f) { int s = atomicAdd(&cnt[wv], 1); if (s < 128) { li[wv][s] = j * 4 + 1; lw[wv][s] = v.y * sc; } }
            if (v.z != 0.f) { int s = atomicAdd(&cnt[wv], 1); if (s < 128) { li[wv][s] = j * 4 + 2; lw[wv][s] = v.z * sc; } }
            if (v.w != 0.f) { int s = atomicAdd(&cnt[wv], 1); if (s < 128) { li[wv][s] = j * 4 + 3; lw[wv][s] = v.w * sc; } }
        }
        int n = cnt[wv] < 128 ? cnt[wv] : 128;
        size_t base = ((size_t)br * 1024 + row) * 128;
        for (int k = t; k < n; k += 64) { a.idxs[base + k] = li[wv][k]; a.wts[base + k] = lw[wv][k]; }
        if (t == 0) a.cnts[br * 1024 + row] = n;
    }
}

// ---------------- segmented MFMA GEMM, 128x128 tile, global_load_lds staged ----
// m97 structure: 256 thr / 4 waves (2x2), wave-tile 64x64, acc[4][4], BK=32.
// LDS: 8 A-subtiles + 8 B-subtiles of [16 rows x 32 k] in lane-consumption order
// (linear dest for global_load_lds; conflict-free ds_read_b128).
struct GSeg {
    const unsigned short* A;    // [Mseg, K] bf16
    const unsigned short* Bt;   // [N, K] bf16
    const unsigned short* Bt2;  // alt weights for local rows >= m_split
    const float* bias;
    const float* bias2;
    unsigned short* Cbf;        // bf16 out for rows < cbf_mlimit
    unsigned short* Cbf2;       // bf16 out for rows >= cbf_mlimit
    int cbf_mlimit;
    int m_split;
    int K;
    int act;
    int mt0;                    // first 128-row m-tile of this segment
};
struct GArr { GSeg s[2]; int ns; int N; };

__global__ __launch_bounds__(256) void gemm_seg_kernel(GArr g) {
    __shared__ unsigned short As[8 * 512];
    __shared__ unsigned short Bs[8 * 512];
    int bx = blockIdx.x, by = blockIdx.y;
    xcd_remap(bx, by, gridDim.x, gridDim.y);
    const int mt = by;
    const int si = (g.ns > 1 && mt >= g.s[1].mt0) ? 1 : 0;
    const GSeg s = g.s[si];
    const int K = s.K, N = g.N;
    const int tid = threadIdx.x;
    const int w = tid >> 6, lane = tid & 63;
    const int wr = w >> 1, wc = w & 1;
    const int lr = lane & 15, lk = lane >> 4;
    const int bm = (mt - s.mt0) * 128, bn = bx * 128;
    const unsigned short* Bu = s.Bt;
    const float* bu = s.bias;
    if (bm >= s.m_split) { Bu = s.Bt2; bu = s.bias2; }

    // wave w stages A-subtiles 2w,2w+1 and B-subtiles 2w,2w+1
    const unsigned short* ga0 = s.A + (size_t)(bm + (2 * w)     * 16 + lr) * K + lk * 8;
    const unsigned short* ga1 = s.A + (size_t)(bm + (2 * w + 1) * 16 + lr) * K + lk * 8;
    const unsigned short* gb0 = Bu  + (size_t)(bn + (2 * w)     * 16 + lr) * K + lk * 8;
    const unsigned short* gb1 = Bu  + (size_t)(bn + (2 * w + 1) * 16 + lr) * K + lk * 8;
    unsigned short* la0 = &As[(2 * w) * 512];
    unsigned short* la1 = &As[(2 * w + 1) * 512];
    unsigned short* lb0 = &Bs[(2 * w) * 512];
    unsigned short* lb1 = &Bs[(2 * w + 1) * 512];

    f32x4 acc[4][4] = {};
    for (int k0 = 0; k0 < K; k0 += 32) {
        GLOAD16(ga0 + k0, la0);
        GLOAD16(ga1 + k0, la1);
        GLOAD16(gb0 + k0, lb0);
        GLOAD16(gb1 + k0, lb1);
        __syncthreads();   // drains vmcnt -> tile resident
        short8 a[4], b[4];
        #pragma unroll
        for (int i = 0; i < 4; ++i)
            a[i] = *reinterpret_cast<const short8*>(&As[(4 * wr + i) * 512 + lane * 8]);
        #pragma unroll
        for (int j = 0; j < 4; ++j)
            b[j] = *reinterpret_cast<const short8*>(&Bs[(4 * wc + j) * 512 + lane * 8]);
        #pragma unroll
        for (int i = 0; i < 4; ++i)
            #pragma unroll
            for (int j = 0; j < 4; ++j)
                acc[i][j] = __builtin_amdgcn_mfma_f32_16x16x32_bf16(a[i], b[j], acc[i][j], 0, 0, 0);
        __syncthreads();   // LDS reads done before next stage overwrites
    }
    #pragma unroll
    for (int i = 0; i < 4; ++i) {
        #pragma unroll
        for (int j = 0; j < 4; ++j) {
            int gcol = bn + wc * 64 + j * 16 + lr;
            float bv = bu ? bu[gcol] : 0.f;
            #pragma unroll
            for (int r = 0; r < 4; ++r) {
                int grow = bm + wr * 64 + i * 16 + lk * 4 + r;
                float v = apply_act(acc[i][j][r] + bv, s.act);
                if (grow < s.cbf_mlimit) {
                    if (s.Cbf)  s.Cbf[(size_t)grow * N + gcol] = f2bf(v);
                } else {
                    if (s.Cbf2) s.Cbf2[(size_t)(grow - s.cbf_mlimit) * N + gcol] = f2bf(v);
                }
            }
        }
    }
}

// ---------------- split-K MFMA GEMM (fp32 partial planes), 64x64 ----------------
// ksplit must be a multiple of 128.
struct KBufs { short8 a0, a1, b0, b1; };

__global__ __launch_bounds__(256) void gemm_splitk_kernel(
    const unsigned short* __restrict__ A, const unsigned short* __restrict__ Bt,
    const unsigned short* __restrict__ Bt2, int m_split,
    float* __restrict__ C, int M, int K, int N, int ksplit) {
    int bx = blockIdx.x, by = blockIdx.y;
    xcd_remap(bx, by, gridDim.x, gridDim.y);
    const int tid = threadIdx.x;
    const int w = tid >> 6, lane = tid & 63;
    const int wr = w >> 1, wc = w & 1;
    const int lr = lane & 15, lk = lane >> 4;
    const int bm = by * 64, bn = bx * 64;
    const int z = blockIdx.z;
    const int kbeg = z * ksplit;
    const int kend = kbeg + ksplit < K ? kbeg + ksplit : K;
    const int KL = kend - kbeg;
    C += (size_t)z * M * N;
    const unsigned short* Bu = (bm >= m_split) ? Bt2 : Bt;

    const unsigned short* Ap = A + (size_t)(bm + wr * 32 + lr) * K + kbeg + lk * 8;
    const unsigned short* Bp = Bu + (size_t)(bn + wc * 32 + lr) * K + kbeg + lk * 8;
    const size_t r16 = (size_t)16 * K;

    f32x4 acc[2][2] = {};
    KBufs u0, u1, u2, u3;
    auto LD = [&](KBufs& u, int kk) {
        kk = kk < KL ? kk : 0;
        u.a0 = *reinterpret_cast<const short8*>(Ap + kk);
        u.a1 = *reinterpret_cast<const short8*>(Ap + r16 + kk);
        u.b0 = *reinterpret_cast<const short8*>(Bp + kk);
        u.b1 = *reinterpret_cast<const short8*>(Bp + r16 + kk);
    };
    auto MM = [&](const KBufs& u) {
        acc[0][0] = __builtin_amdgcn_mfma_f32_16x16x32_bf16(u.a0, u.b0, acc[0][0], 0, 0, 0);
        acc[0][1] = __builtin_amdgcn_mfma_f32_16x16x32_bf16(u.a0, u.b1, acc[0][1], 0, 0, 0);
        acc[1][0] = __builtin_amdgcn_mfma_f32_16x16x32_bf16(u.a1, u.b0, acc[1][0], 0, 0, 0);
        acc[1][1] = __builtin_amdgcn_mfma_f32_16x16x32_bf16(u.a1, u.b1, acc[1][1], 0, 0, 0);
    };
    LD(u0, 0); LD(u1, 32); LD(u2, 64);
    for (int k = 0; k < KL; k += 128) {
        LD(u3, k + 96);  MM(u0);
        LD(u0, k + 128); MM(u1);
        LD(u1, k + 160); MM(u2);
        LD(u2, k + 192); MM(u3);
    }
    #pragma unroll
    for (int i = 0; i < 2; ++i)
        #pragma unroll
        for (int j = 0; j < 2; ++j) {
            int gcol = bn + wc * 32 + j * 16 + lr;
            #pragma unroll
            for (int r = 0; r < 4; ++r) {
                int grow = bm + wr * 32 + i * 16 + lk * 4 + r;
                C[(size_t)grow * N + gcol] = acc[i][j][r];
            }
        }
}

// ---------------- sparse ops ----------------
__global__ __launch_bounds__(256) void neiagg_kernel(
    const float* __restrict__ nei0, const float* __restrict__ nei1,
    const unsigned short* __restrict__ hn0, const unsigned short* __restrict__ hn1,
    unsigned short* __restrict__ hagg) {
    const int row = blockIdx.x, br = blockIdx.y, t = threadIdx.x;
    const float* nei = br ? nei1 : nei0;
    const unsigned short* hn = br ? hn1 : hn0;
    __shared__ int idxs[256];
    __shared__ int cnt;
    if (t == 0) cnt = 0;
    __syncthreads();
    const float4* nr = reinterpret_cast<const float4*>(nei + (size_t)row * 4096);
    for (int j = t; j < 1024; j += 256) {
        float4 v = nr[j];
        if (v.x != 0.f) { int s = atomicAdd(&cnt, 1); if (s < 256) idxs[s] = j * 4 + 0; }
        if (v.y != 0.f) { int s = atomicAdd(&cnt, 1); if (s < 256) idxs[s] = j * 4 + 1; }
        if (v.z != 0.f) { int s = atomicAdd(&cnt, 1); if (s < 256) idxs[s] = j * 4 + 2; }
        if (v.w != 0.f) { int s = atomicAdd(&cnt, 1); if (s < 256) idxs[s] = j * 4 + 3; }
    }
    __syncthreads();
    int n = cnt < 256 ? cnt : 256;
    float inv = frcp(fmaxf((float)cnt, 1.f));
    int c = t * 2;
    float a0 = 0.f, a1 = 0.f, b0 = 0.f, b1 = 0.f;
    int k = 0;
    for (; k + 2 <= n; k += 2) {
        ushort2 u = *reinterpret_cast<const ushort2*>(&hn[(size_t)idxs[k] * 512 + c]);
        ushort2 v = *reinterpret_cast<const ushort2*>(&hn[(size_t)idxs[k + 1] * 512 + c]);
        a0 += bf2f(u.x); a1 += bf2f(u.y);
        b0 += bf2f(v.x); b1 += bf2f(v.y);
    }
    if (k < n) {
        ushort2 u = *reinterpret_cast<const ushort2*>(&hn[(size_t)idxs[k] * 512 + c]);
        a0 += bf2f(u.x); a1 += bf2f(u.y);
    }
    ushort2 o; o.x = f2bf((a0 + b0) * inv); o.y = f2bf((a1 + b1) * inv);
    *reinterpret_cast<ushort2*>(&hagg[((size_t)br * 1024 + row) * 512 + c]) = o;
}

// views/masks; h_tar/h_mask bf16; tbuf has 2 split-K planes (stride PL)
__global__ void addelu_kernel(const unsigned short* __restrict__ ht,
                              const unsigned short* __restrict__ hm,
                              const float* __restrict__ tt, unsigned short* __restrict__ xcat,
                              int nh, int PL) {
    int idx = blockIdx.x * 256 + threadIdx.x;
    if (idx < nh) {
        float h1 = bf2f(ht[idx]), h2 = bf2f(hm[idx]);
        float t0 = tt[idx] + tt[idx + PL];
        float t1 = tt[idx + nh] + tt[idx + nh + PL];
        float a = h1 + t0, b = h2 + t0, c = h1 + t1, d = h2 + t1;
        xcat[(size_t)1 * nh + idx] = f2bf(a > 0.f ? a : fexp(a) - 1.f);
        xcat[(size_t)2 * nh + idx] = f2bf(b > 0.f ? b : fexp(b) - 1.f);
        xcat[(size_t)3 * nh + idx] = f2bf(c > 0.f ? c : fexp(c) - 1.f);
        xcat[(size_t)4 * nh + idx] = f2bf(d > 0.f ? d : fexp(d) - 1.f);
    }
}

// h1cat[br] = bf16(relu(adj_br @ (X0+X1)[br] + b1)); X has 2 split-K planes stride PL
__global__ __launch_bounds__(256) void spmm1_kernel(
    const int* __restrict__ cnts, const int* __restrict__ idxs, const float* __restrict__ wts,
    const float* __restrict__ X, int PL, const float* __restrict__ bias,
    unsigned short* __restrict__ out) {
    const int row = blockIdx.x * 4 + (threadIdx.x >> 6);
    const int br = blockIdx.y, t = threadIdx.x & 63;
    size_t base = ((size_t)br * 1024 + row) * 128;
    int n = cnts[br * 1024 + row];
    const float* Xb = X + (size_t)br * 1024 * 64;
    const float* Xb2 = Xb + PL;
    float acc = bias[t], a1 = 0.f;
    int k = 0;
    for (; k + 2 <= n; k += 2) {
        int   i0 = idxs[base + k], i1 = idxs[base + k + 1];
        float w0 = wts[base + k],  w1 = wts[base + k + 1];
        acc += w0 * (Xb[(size_t)i0 * 64 + t] + Xb2[(size_t)i0 * 64 + t]);
        a1  += w1 * (Xb[(size_t)i1 * 64 + t] + Xb2[(size_t)i1 * 64 + t]);
    }
    if (k < n) {
        int i0 = idxs[base + k];
        acc += wts[base + k] * (Xb[(size_t)i0 * 64 + t] + Xb2[(size_t)i0 * 64 + t]);
    }
    acc += a1;
    out[((size_t)br * 1024 + row) * 64 + t] = f2bf(fmaxf(acc, 0.f));
}

// Fused: g = adj_br @ h1 (gather bf16), o = g @ w2 + b2; br0 -> zcf_bf;
// br1..4 -> l2norm(o) -> hs + att row value.
__global__ __launch_bounds__(256) void spmm2_kernel(
    const int* __restrict__ cnts, const int* __restrict__ idxs, const float* __restrict__ wts,
    const unsigned short* __restrict__ H1, const float* __restrict__ w2,
    const float* __restrict__ b2, unsigned short* __restrict__ zcf_bf,
    float* __restrict__ hs, const float* __restrict__ att_w,
    const float* __restrict__ att_b, const float* __restrict__ att_vec,
    float* __restrict__ att_row) {
    const int wv = threadIdx.x >> 6;
    const int row = blockIdx.x * 4 + wv;
    const int br = blockIdx.y, t = threadIdx.x & 63;
    size_t base = ((size_t)br * 1024 + row) * 128;
    int n = cnts[br * 1024 + row];
    const unsigned short* Hb = H1 + (size_t)br * 1024 * 64;
    float g0 = 0.f, g1 = 0.f, g2 = 0.f, g3 = 0.f;
    int k = 0;
    for (; k + 4 <= n; k += 4) {
        g0 += wts[base + k]     * bf2f(Hb[(size_t)idxs[base + k]     * 64 + t]);
        g1 += wts[base + k + 1] * bf2f(Hb[(size_t)idxs[base + k + 1] * 64 + t]);
        g2 += wts[base + k + 2] * bf2f(Hb[(size_t)idxs[base + k + 2] * 64 + t]);
        g3 += wts[base + k + 3] * bf2f(Hb[(size_t)idxs[base + k + 3] * 64 + t]);
    }
    for (; k < n; ++k) g0 += wts[base + k] * bf2f(Hb[(size_t)idxs[base + k] * 64 + t]);
    float g = (g0 + g1) + (g2 + g3);
    __shared__ float rs[4][64];
    rs[wv][t] = g;   // same-wave write/read: lockstep, no barrier
    float o = b2[t];
    #pragma unroll
    for (int c = 0; c < 64; ++c) o += rs[wv][c] * w2[c * 64 + t];
    if (br == 0) {
        zcf_bf[(size_t)row * 64 + t] = f2bf(o);
        return;
    }
    float s = o * o;
    #pragma unroll
    for (int q = 32; q; q >>= 1) s += __shfl_down(s, q);
    s = __shfl(s, 0);
    float v = o * frcp(fmaxf(sqrtf(s), 1e-12f));
    hs[((size_t)(br - 1) * 1024 + row) * 64 + t] = v;
    rs[wv][t] = v;   // safe overwrite (wave-sync)
    float sa = att_b[t];
    #pragma unroll
    for (int c = 0; c < 64; ++c) sa += rs[wv][c] * att_w[c * 64 + t];
    float val = ftanh(sa) * att_vec[t];
    #pragma unroll
    for (int q = 32; q; q >>= 1) val += __shfl_down(val, q);
    if (t == 0) att_row[(size_t)(br - 1) * 1024 + row] = val;
}

__global__ __launch_bounds__(256) void attreduce_kernel(const float* __restrict__ att_row,
                                                        float* __restrict__ small) {
    const int v = blockIdx.x, t = threadIdx.x;
    const float* p = att_row + (size_t)v * 1024;
    float s = p[t] + p[t + 256] + p[t + 512] + p[t + 768];
    #pragma unroll
    for (int o = 32; o; o >>= 1) s += __shfl_down(s, o);
    __shared__ float ps[4];
    if ((t & 63) == 0) ps[t >> 6] = s;
    __syncthreads();
    if (t == 0) small[v] = ps[0] + ps[1] + ps[2] + ps[3];
}

// Fused projection head: rows [0,N) z_coarse (from zcf_bf), rows [N,2N) z_fine
__global__ __launch_bounds__(256) void projhead_kernel(
    const unsigned short* __restrict__ zcf_bf, const float* __restrict__ hs,
    const float* __restrict__ small, const float* __restrict__ proj_w,
    const float* __restrict__ proj_b, const float* __restrict__ mlp1_w,
    float* __restrict__ zcat, float* __restrict__ AC1) {
    const int wv = threadIdx.x >> 6;
    const int row = blockIdx.x * 4 + wv;
    const int t = threadIdx.x & 63;
    float zv;
    if (row < 1024) {
        zv = bf2f(zcf_bf[(size_t)row * 64 + t]);
    } else {
        int r = row - 1024;
        float e0 = small[0] * (1.f / 1024.f), e1 = small[1] * (1.f / 1024.f);
        float e2 = small[2] * (1.f / 1024.f), e3 = small[3] * (1.f / 1024.f);
        float mx = fmaxf(fmaxf(e0, e1), fmaxf(e2, e3));
        float x0 = expf(e0 - mx), x1 = expf(e1 - mx), x2 = expf(e2 - mx), x3 = expf(e3 - mx);
        float inv = 1.f / (x0 + x1 + x2 + x3);
        size_t ix = (size_t)r * 64 + t;
        zv = (x0 * hs[ix] + x1 * hs[ix + 65536] +
              x2 * hs[ix + 131072] + x3 * hs[ix + 196608]) * inv;
    }
    __shared__ float rs[4][64];
    rs[wv][t] = zv;
    float p = proj_b[t];
    #pragma unroll
    for (int c = 0; c < 64; ++c) p += rs[wv][c] * proj_w[c * 64 + t];
    p = ftanh(p);
    float s = p * p;
    #pragma unroll
    for (int q = 32; q; q >>= 1) s += __shfl_down(s, q);
    s = __shfl(s, 0);
    float r = p * frcp(fmaxf(sqrtf(s), 1e-12f));
    zcat[(size_t)row * 64 + t] = r;
    rs[wv][t] = r;
    if (t < 16) {
        float a = 0.f;
        #pragma unroll
        for (int c = 0; c < 64; ++c) a += rs[wv][c] * mlp1_w[c * 16 + t];
        AC1[(size_t)row * 16 + t] = a;
    }
}

// 4 anchors per block; per-block partial written to loss_part[bid] (no atomics/memset)
__global__ __launch_bounds__(256) void infonce_kernel(
    const float* __restrict__ zf, const float* __restrict__ zc,
    const float* __restrict__ A1, const float* __restrict__ C1,
    const float* __restrict__ b1, const float* __restrict__ m2,
    const float* __restrict__ b2v, float* __restrict__ loss_part) {
    const int i0 = blockIdx.x * 4, t = threadIdx.x;
    __shared__ __align__(16) float zfs[4][64];
    __shared__ float a1b[4][16], m2s[16];
    __shared__ float diag[4];
    __shared__ float wsum[4][4];
    if (t < 64) {
        #pragma unroll
        for (int ii = 0; ii < 4; ++ii) zfs[ii][t] = zf[(size_t)(i0 + ii) * 64 + t];
    }
    if (t < 16) {
        float bb = b1[t];
        #pragma unroll
        for (int ii = 0; ii < 4; ++ii) a1b[ii][t] = A1[(size_t)(i0 + ii) * 16 + t] + bb;
        m2s[t] = m2[t];
    }
    __syncthreads();
    const float b2 = b2v[0];
    float acc[4] = {};
    for (int j = t; j < 1024; j += 256) {
        const float4* zcj = reinterpret_cast<const float4*>(zc + (size_t)j * 64);
        float dot[4] = {};
        #pragma unroll
        for (int e = 0; e < 16; ++e) {
            float4 b = zcj[e];
            #pragma unroll
            for (int ii = 0; ii < 4; ++ii) {
                float4 a = reinterpret_cast<const float4*>(zfs[ii])[e];
                dot[ii] += a.x * b.x + a.y * b.y + a.z * b.z + a.w * b.w;
            }
        }
        float c1j[16];
        #pragma unroll
        for (int q = 0; q < 4; ++q) {
            float4 c4 = reinterpret_cast<const float4*>(C1 + (size_t)j * 16)[q];
            c1j[q * 4 + 0] = c4.x; c1j[q * 4 + 1] = c4.y;
            c1j[q * 4 + 2] = c4.z; c1j[q * 4 + 3] = c4.w;
        }
        #pragma unroll
        for (int ii = 0; ii < 4; ++ii) {
            float logit = dot[ii] * 2.0f; // 1/TAU
            float h = b2;
            #pragma unroll
            for (int k = 0; k < 16; ++k) h += ftanh(a1b[ii][k] + c1j[k]) * m2s[k];
            acc[ii] += fexp(logit) * fsigmoid(h);
            if (j == i0 + ii) diag[ii] = logit;
        }
    }
    #pragma unroll
    for (int ii = 0; ii < 4; ++ii) {
        float a = acc[ii];
        #pragma unroll
        for (int o = 32; o; o >>= 1) a += __shfl_down(a, o);
        if ((t & 63) == 0) wsum[t >> 6][ii] = a;
    }
    __syncthreads();
    if (t == 0) {
        float part = 0.f;
        #pragma unroll
        for (int ii = 0; ii < 4; ++ii) {
            float denom = wsum[0][ii] + wsum[1][ii] + wsum[2][ii] + wsum[3][ii];
            part += logf(denom) - diag[ii];
        }
        loss_part[blockIdx.x] = part;
    }
}

// sum 256 per-block partials -> loss / 1024
__global__ __launch_bounds__(256) void finalize_kernel(const float* __restrict__ loss_part,
                                                       float* __restrict__ out) {
    const int t = threadIdx.x;
    float s = loss_part[t];
    #pragma unroll
    for (int o = 32; o; o >>= 1) s += __shfl_down(s, o);
    __shared__ float ps[4];
    if ((t & 63) == 0) ps[t >> 6] = s;
    __syncthreads();
    if (t == 0) out[0] = (ps[0] + ps[1] + ps[2] + ps[3]) * (1.f / 1024.f);
}

extern "C" void kernel_launch(void* const* d_in, const int* in_sizes, int n_in,
                              void* d_out, int out_size, void* d_ws, size_t ws_size,
                              hipStream_t stream) {
    const float* feat0     = (const float*)d_in[0];
    const float* feat1     = (const float*)d_in[1];
    const float* feat2     = (const float*)d_in[2];
    const float* mask_feat = (const float*)d_in[3];
    const float* nei0      = (const float*)d_in[4];
    const float* nei1      = (const float*)d_in[5];
    const float* adj0      = (const float*)d_in[6];
    const float* adj1      = (const float*)d_in[7];
    const float* madj0     = (const float*)d_in[8];
    const float* madj1     = (const float*)d_in[9];
    const float* fc0_w = (const float*)d_in[10];
    const float* fc0_b = (const float*)d_in[11];
    const float* fc1_w = (const float*)d_in[12];
    const float* fc1_b = (const float*)d_in[13];
    const float* fc2_w = (const float*)d_in[14];
    const float* fc2_b = (const float*)d_in[15];
    const float* agg0_w = (const float*)d_in[16];
    const float* agg1_w = (const float*)d_in[17];
    const float* gcn_w1 = (const float*)d_in[18];
    const float* gcn_b1 = (const float*)d_in[19];
    const float* gcn_w2 = (const float*)d_in[20];
    const float* gcn_b2 = (const float*)d_in[21];
    const float* att_w  = (const float*)d_in[22];
    const float* att_b  = (const float*)d_in[23];
    const float* att_vec = (const float*)d_in[24];
    const float* proj_w = (const float*)d_in[25];
    const float* proj_b = (const float*)d_in[26];
    const float* mlp1_w = (const float*)d_in[27];
    const float* mlp1_b = (const float*)d_in[28];
    const float* mlp2_w = (const float*)d_in[29];
    const float* mlp2_b = (const float*)d_in[30];

    const int N = 1024, M = 4096, D0 = 1024, D1 = 512, H = 512, E = 64;
    typedef unsigned short bf;

    // ---- workspace ----
    float* W = (float*)d_ws;
    size_t off = 0;
    auto allocf = [&](size_t n) { float* p = W + off; off += n; return p; };
    float* tbuf    = allocf((size_t)2 * 2 * N * H); // 2 split-K planes
    float* xw1cat  = allocf((size_t)2 * 5 * N * E); // 2 split-K planes
    float* hs      = allocf((size_t)4 * N * E);
    float* zcat    = allocf((size_t)2 * N * E);
    float* AC1     = allocf((size_t)2 * N * 16);
    float* att_row = allocf((size_t)4 * N);
    float* small   = allocf(16);
    float* loss_part = allocf(256);
    float* adj_wts = allocf((size_t)5 * 1024 * 128);
    int*   adj_idx = (int*)allocf((size_t)5 * 1024 * 128);
    int*   adj_cnt = (int*)allocf((size_t)5 * 1024);
    bf* BP = (bf*)(W + off);
    size_t boff = 0;
    auto allocb = [&](size_t n) { bf* p = BP + boff; boff += n; return p; };
    bf* feat0_bf = allocb((size_t)N * D0);   // feat0 | mask contiguous
    bf* mask_bf  = allocb((size_t)N * D0);
    bf* feat1_bf = allocb((size_t)M * D1);   // feat1 | feat2 contiguous
    bf* feat2_bf = allocb((size_t)M * D1);
    bf* xcat_bf  = allocb((size_t)5 * N * H); // branch0 = h_tar bf16
    bf* hmask_bf = allocb((size_t)N * H);
    bf* hnei0_bf = allocb((size_t)M * H);    // hnei0 | hnei1 contiguous
    bf* hnei1_bf = allocb((size_t)M * H);
    bf* hagg_bf  = allocb((size_t)2 * N * H);
    bf* h1cat_bf = allocb((size_t)5 * N * E);
    bf* zcf_bf   = allocb((size_t)N * E);
    bf* fc0_wT  = allocb((size_t)H * D0);
    bf* fc1_wT  = allocb((size_t)H * D1);
    bf* fc2_wT  = allocb((size_t)H * D1);
    bf* agg0_wT = allocb((size_t)H * H);
    bf* agg1_wT = allocb((size_t)H * H);
    bf* gw1_T   = allocb((size_t)E * H);

    // single merged prep launch: 6 weight transposes + 4 input casts + adjprep
    {
        CastArr a; int tile = 0, i = 0;
        auto addT = [&](const float* in, bf* out, int R, int C) {
            int tc = (C + 31) / 32, trn = (R + 31) / 32;
            a.t[i++] = CTDesc{in, out, R, C, tc, tile};
            tile += tc * trn;
        };
        addT(fc0_w, fc0_wT, D0, H);
        addT(fc1_w, fc1_wT, D1, H);
        addT(fc2_w, fc2_wT, D1, H);
        addT(agg0_w, agg0_wT, H, H);
        addT(agg1_w, agg1_wT, H, H);
        addT(gcn_w1, gw1_T, H, E);
        a.nt = i; a.T = tile;
        int s4 = 0, fi = 0;
        auto addF = [&](const float* in, bf* out, int n) {
            a.f[fi++] = CMDesc{in, out, s4}; s4 += n / 4;
        };
        addF(feat0, feat0_bf, N * D0);
        addF(mask_feat, mask_bf, N * D0);
        addF(feat1, feat1_bf, M * D1);
        addF(feat2, feat2_bf, M * D1);
        a.nf = fi; a.total4 = s4; a.F = (s4 + 255) / 256;
        a.adj0 = adj0; a.adj1 = adj1; a.madj0 = madj0; a.madj1 = madj1;
        a.cnts = adj_cnt; a.idxs = adj_idx; a.wts = adj_wts;
        int nb = a.T + a.F + (5 * 1024) / 4;
        cast_all_kernel<<<nb, 256, 0, stream>>>(a);
    }

    // merged projections GEMM (128x128 LDS-staged): seg0 [feat0;mask]@fc0 -> [xcat0|hmask],
    // seg1 [feat1;feat2]@fc1/fc2 -> hnei. grid (4, 16+64), XCD-striped.
    {
        GArr g;
        g.s[0] = GSeg{feat0_bf, fc0_wT, nullptr, fc0_b, nullptr,
                      xcat_bf, hmask_bf, N, 1 << 30, D0, ACT_ELU, 0};
        g.s[1] = GSeg{feat1_bf, fc1_wT, fc2_wT, fc1_b, fc2_b,
                      hnei0_bf, nullptr, 2 * M, M, D1, ACT_ELU, 16};
        g.ns = 2; g.N = H;
        gemm_seg_kernel<<<dim3(H / 128, 16 + 64), 256, 0, stream>>>(g);
    }

    // meta-path aggregation
    neiagg_kernel<<<dim3(N, 2), 256, 0, stream>>>(nei0, nei1, hnei0_bf, hnei1_bf, hagg_bf);
    // agg GEMM split-K x2: [hagg0;hagg1]@agg0/agg1 -> 2 fp32 planes in tbuf
    gemm_splitk_kernel<<<dim3(H / 64, 2 * N / 64, 2), 256, 0, stream>>>(
        hagg_bf, agg0_wT, agg1_wT, N, tbuf, 2 * N, H, H, 256);
    addelu_kernel<<<(N * H + 255) / 256, 256, 0, stream>>>(xcat_bf, hmask_bf, tbuf, xcat_bf,
                                                           N * H, 2 * N * H);

    // GCN layer 1: xcat@gw1 split-K x2 -> 2 planes, then spmm1 (sums planes)
    gemm_splitk_kernel<<<dim3(1, 5 * N / 64, 2), 256, 0, stream>>>(
        xcat_bf, gw1_T, nullptr, 1 << 30, xw1cat, 5 * N, H, E, 256);
    spmm1_kernel<<<dim3(N / 4, 5), 256, 0, stream>>>(adj_cnt, adj_idx, adj_wts,
                                                     xw1cat, 5 * N * E, gcn_b1, h1cat_bf);
    // GCN layer 2 fused: spmm2 = gather(h1) @ w2 + b2 (+l2norm +att)
    spmm2_kernel<<<dim3(N / 4, 5), 256, 0, stream>>>(adj_cnt, adj_idx, adj_wts, h1cat_bf,
                                                     gcn_w2, gcn_b2, zcf_bf, hs,
                                                     att_w, att_b, att_vec, att_row);
    attreduce_kernel<<<4, 256, 0, stream>>>(att_row, small);

    // fused zfine + projection + l2norm + mlp1 matvec
    projhead_kernel<<<2 * N / 4, 256, 0, stream>>>(zcf_bf, hs, small, proj_w, proj_b,
                                                   mlp1_w, zcat, AC1);

    // InfoNCE
    const float* zc = zcat;
    const float* zf = zcat + (size_t)N * E;
    const float* C1 = AC1;
    const float* A1 = AC1 + (size_t)N * 16;
    infonce_kernel<<<N / 4, 256, 0, stream>>>(zf, zc, A1, C1, mlp1_b, mlp2_w, mlp2_b, loss_part);

    finalize_kernel<<<1, 256, 0, stream>>>(loss_part, (float*)d_out);
}

// Round 11
// 267.939 us; speedup vs baseline: 1.0907x; 1.0559x over previous
//
#include <hip/hip_runtime.h>

#define ACT_NONE 0
#define ACT_ELU  1
#define ACT_RELU 2
#define ACT_TANH 3

typedef __attribute__((ext_vector_type(8))) short short8;
typedef __attribute__((ext_vector_type(4))) float f32x4;

__device__ __forceinline__ float frcp(float x) { return __builtin_amdgcn_rcpf(x); }
__device__ __forceinline__ float fexp(float x) { return __expf(x); }
// safe fast tanh: 1 - 2/(e^2x + 1). x=+inf -> 1, x=-inf -> -1, no NaN.
__device__ __forceinline__ float ftanh(float x) {
    return 1.f - 2.f * frcp(fexp(2.f * x) + 1.f);
}
__device__ __forceinline__ float fsigmoid(float x) {
    return frcp(1.f + fexp(-x));
}

__device__ __forceinline__ float apply_act(float v, int act) {
    if (act == ACT_ELU)  return v > 0.f ? v : fexp(v) - 1.f;
    if (act == ACT_RELU) return fmaxf(v, 0.f);
    if (act == ACT_TANH) return ftanh(v);
    return v;
}

__device__ __forceinline__ unsigned short f2bf(float f) {
    unsigned int u = __float_as_uint(f);
    unsigned int r = (u + 0x7fffu + ((u >> 16) & 1u)) >> 16;
    return (unsigned short)r;
}
__device__ __forceinline__ float bf2f(unsigned short u) {
    return __uint_as_float(((unsigned int)u) << 16);
}

#define GLOAD16(gp, lp) __builtin_amdgcn_global_load_lds( \
    (const __attribute__((address_space(1))) void*)(gp),  \
    (__attribute__((address_space(3))) void*)(lp), 16, 0, 0)

// XCD-aware remap, STRIPED panels: all nx n-tiles of one A row-panel land on
// the same XCD (panel fetched into one L2, reused nx times); panels striped
// p->p%8 so heterogeneous segments stay balanced. Bijective when ny%8==0.
__device__ __forceinline__ void xcd_remap(int& bx, int& by, int nx, int ny) {
    if ((ny & 7) == 0) {
        int L = by * nx + bx;
        int xcd = L & 7, j = L >> 3;
        int q = j / nx;
        by = xcd + 8 * q;
        bx = j - q * nx;
    }
}

// ---------------- merged prep kernel: weight transposes + input casts + adjprep ----
struct CTDesc { const float* in; unsigned short* out; int R, C, tcols, tile0; };
struct CMDesc { const float* in; unsigned short* out; int start4; };
struct CastArr {
    CTDesc t[8]; int nt; int T;
    CMDesc f[6]; int nf; int total4; int F;
    // adjprep
    const float* adj0; const float* adj1; const float* madj0; const float* madj1;
    int* cnts; int* idxs; float* wts;
};

__global__ __launch_bounds__(256) void cast_all_kernel(CastArr a) {
    int b = blockIdx.x;
    __shared__ float tt[32][33];
    __shared__ int li[4][128];
    __shared__ float lw[4][128];
    __shared__ int cnt[4];
    if (b < a.T) {
        int s = 0;
        while (s + 1 < a.nt && b >= a.t[s + 1].tile0) ++s;
        const CTDesc d = a.t[s];
        int lt = b - d.tile0;
        int tr = lt / d.tcols, tc = lt % d.tcols;
        int r0 = tr * 32, c0 = tc * 32;
        int tx = threadIdx.x & 31, ty = threadIdx.x >> 5; // 32 x 8
        for (int i = ty; i < 32; i += 8) {
            int r = r0 + i, c = c0 + tx;
            tt[i][tx] = (r < d.R && c < d.C) ? d.in[(size_t)r * d.C + c] : 0.f;
        }
        __syncthreads();
        for (int i = ty; i < 32; i += 8) {
            int c = c0 + i, r = r0 + tx;
            if (c < d.C && r < d.R) d.out[(size_t)c * d.R + r] = f2bf(tt[tx][i]);
        }
    } else if (b < a.T + a.F) {
        int g4 = (b - a.T) * 256 + threadIdx.x;
        if (g4 >= a.total4) return;
        int s = 0;
        while (s + 1 < a.nf && g4 >= a.f[s + 1].start4) ++s;
        int l4 = g4 - a.f[s].start4;
        float4 v = *reinterpret_cast<const float4*>(a.f[s].in + (size_t)l4 * 4);
        ushort4 o;
        o.x = f2bf(v.x); o.y = f2bf(v.y); o.z = f2bf(v.z); o.w = f2bf(v.w);
        *reinterpret_cast<ushort4*>(a.f[s].out + (size_t)l4 * 4) = o;
    } else {
        // adjprep: one wave per (row, br) pair. br0=0.5*(adj0+adj1),1=adj0,2=madj0,3=adj1,4=madj1
        int wv = threadIdx.x >> 6, t = threadIdx.x & 63;
        int p = (b - a.T - a.F) * 4 + wv;     // 0..5119
        int row = p & 1023, br = p >> 10;
        const float* Aa; const float* Ab = nullptr; float sc = 1.f;
        if (br == 0)      { Aa = a.adj0; Ab = a.adj1; sc = 0.5f; }
        else if (br == 1) { Aa = a.adj0; }
        else if (br == 2) { Aa = a.madj0; }
        else if (br == 3) { Aa = a.adj1; }
        else              { Aa = a.madj1; }
        if (t == 0) cnt[wv] = 0;
        // wave-private shared: lockstep within wave, no barrier needed
        const float4* ar = reinterpret_cast<const float4*>(Aa + (size_t)row * 1024);
        const float4* brp = Ab ? reinterpret_cast<const float4*>(Ab + (size_t)row * 1024) : nullptr;
        for (int j = t; j < 256; j += 64) {
            float4 v = ar[j];
            if (brp) { float4 u = brp[j]; v.x += u.x; v.y += u.y; v.z += u.z; v.w += u.w; }
            if (v.x != 0.f) { int s = atomicAdd(&cnt[wv], 1); if (s < 128) { li[wv][s] = j * 4 + 0; lw[wv][s] = v.x * sc; } }
            if (v.y != 0.f) { int s = atomicAdd(&cnt[wv], 1); if (s < 128) { li[wv][s] = j * 4 + 1; lw[wv][s] = v.y * sc; } }
            if (v.z != 0.f) { int s = atomicAdd(&cnt[wv], 1); if (s < 128) { li[wv][s] = j * 4 + 2; lw[wv][s] = v.z * sc; } }
            if (v.w != 0.f) { int s = atomicAdd(&cnt[wv], 1); if (s < 128) { li[wv][s] = j * 4 + 3; lw[wv][s] = v.w * sc; } }
        }
        int n = cnt[wv] < 128 ? cnt[wv] : 128;
        size_t base = ((size_t)br * 1024 + row) * 128;
        for (int k = t; k < n; k += 64) { a.idxs[base + k] = li[wv][k]; a.wts[base + k] = lw[wv][k]; }
        if (t == 0) a.cnts[br * 1024 + row] = n;
    }
}

// ---------------- segmented MFMA GEMM, 64x64 tile, global_load_lds staged ----
// 256 thr / 4 waves (2x2), wave-tile 32x32, acc[2][2], BK=32. Grid 1280 blocks
// (5 blocks/CU): co-resident blocks hide each other's barrier drains (m114).
// LDS: 4 A-subtiles + 4 B-subtiles of [16 rows x 32 k] in lane-consumption
// order (linear dest for global_load_lds; conflict-free ds_read_b128).
struct GSeg {
    const unsigned short* A;    // [Mseg, K] bf16
    const unsigned short* Bt;   // [N, K] bf16
    const unsigned short* Bt2;  // alt weights for local rows >= m_split
    const float* bias;
    const float* bias2;
    unsigned short* Cbf;        // bf16 out for rows < cbf_mlimit
    unsigned short* Cbf2;       // bf16 out for rows >= cbf_mlimit
    int cbf_mlimit;
    int m_split;
    int K;
    int act;
    int mt0;                    // first 64-row m-tile of this segment
};
struct GArr { GSeg s[2]; int ns; int N; };

__global__ __launch_bounds__(256) void gemm_seg_kernel(GArr g) {
    __shared__ unsigned short As[4 * 512];
    __shared__ unsigned short Bs[4 * 512];
    int bx = blockIdx.x, by = blockIdx.y;
    xcd_remap(bx, by, gridDim.x, gridDim.y);
    const int mt = by;
    const int si = (g.ns > 1 && mt >= g.s[1].mt0) ? 1 : 0;
    const GSeg s = g.s[si];
    const int K = s.K, N = g.N;
    const int tid = threadIdx.x;
    const int w = tid >> 6, lane = tid & 63;
    const int wr = w >> 1, wc = w & 1;
    const int lr = lane & 15, lk = lane >> 4;
    const int bm = (mt - s.mt0) * 64, bn = bx * 64;
    const unsigned short* Bu = s.Bt;
    const float* bu = s.bias;
    if (bm >= s.m_split) { Bu = s.Bt2; bu = s.bias2; }

    // wave w stages A-subtile w and B-subtile w (1 GLOAD16 each = 16 rows x 32 k)
    const unsigned short* ga = s.A + (size_t)(bm + w * 16 + lr) * K + lk * 8;
    const unsigned short* gb = Bu  + (size_t)(bn + w * 16 + lr) * K + lk * 8;
    unsigned short* la = &As[w * 512];
    unsigned short* lb = &Bs[w * 512];

    f32x4 acc[2][2] = {};
    for (int k0 = 0; k0 < K; k0 += 32) {
        GLOAD16(ga + k0, la);
        GLOAD16(gb + k0, lb);
        __syncthreads();   // drains vmcnt -> tile resident
        short8 a[2], b[2];
        #pragma unroll
        for (int i = 0; i < 2; ++i)
            a[i] = *reinterpret_cast<const short8*>(&As[(2 * wr + i) * 512 + lane * 8]);
        #pragma unroll
        for (int j = 0; j < 2; ++j)
            b[j] = *reinterpret_cast<const short8*>(&Bs[(2 * wc + j) * 512 + lane * 8]);
        #pragma unroll
        for (int i = 0; i < 2; ++i)
            #pragma unroll
            for (int j = 0; j < 2; ++j)
                acc[i][j] = __builtin_amdgcn_mfma_f32_16x16x32_bf16(a[i], b[j], acc[i][j], 0, 0, 0);
        __syncthreads();   // LDS reads done before next stage overwrites
    }
    #pragma unroll
    for (int i = 0; i < 2; ++i) {
        #pragma unroll
        for (int j = 0; j < 2; ++j) {
            int gcol = bn + wc * 32 + j * 16 + lr;
            float bv = bu ? bu[gcol] : 0.f;
            #pragma unroll
            for (int r = 0; r < 4; ++r) {
                int grow = bm + wr * 32 + i * 16 + lk * 4 + r;
                float v = apply_act(acc[i][j][r] + bv, s.act);
                if (grow < s.cbf_mlimit) {
                    if (s.Cbf)  s.Cbf[(size_t)grow * N + gcol] = f2bf(v);
                } else {
                    if (s.Cbf2) s.Cbf2[(size_t)(grow - s.cbf_mlimit) * N + gcol] = f2bf(v);
                }
            }
        }
    }
}

// ---------------- split-K MFMA GEMM (fp32 partial planes), 64x64 ----------------
// ksplit must be a multiple of 128.
struct KBufs { short8 a0, a1, b0, b1; };

__global__ __launch_bounds__(256) void gemm_splitk_kernel(
    const unsigned short* __restrict__ A, const unsigned short* __restrict__ Bt,
    const unsigned short* __restrict__ Bt2, int m_split,
    float* __restrict__ C, int M, int K, int N, int ksplit) {
    int bx = blockIdx.x, by = blockIdx.y;
    xcd_remap(bx, by, gridDim.x, gridDim.y);
    const int tid = threadIdx.x;
    const int w = tid >> 6, lane = tid & 63;
    const int wr = w >> 1, wc = w & 1;
    const int lr = lane & 15, lk = lane >> 4;
    const int bm = by * 64, bn = bx * 64;
    const int z = blockIdx.z;
    const int kbeg = z * ksplit;
    const int kend = kbeg + ksplit < K ? kbeg + ksplit : K;
    const int KL = kend - kbeg;
    C += (size_t)z * M * N;
    const unsigned short* Bu = (bm >= m_split) ? Bt2 : Bt;

    const unsigned short* Ap = A + (size_t)(bm + wr * 32 + lr) * K + kbeg + lk * 8;
    const unsigned short* Bp = Bu + (size_t)(bn + wc * 32 + lr) * K + kbeg + lk * 8;
    const size_t r16 = (size_t)16 * K;

    f32x4 acc[2][2] = {};
    KBufs u0, u1, u2, u3;
    auto LD = [&](KBufs& u, int kk) {
        kk = kk < KL ? kk : 0;
        u.a0 = *reinterpret_cast<const short8*>(Ap + kk);
        u.a1 = *reinterpret_cast<const short8*>(Ap + r16 + kk);
        u.b0 = *reinterpret_cast<const short8*>(Bp + kk);
        u.b1 = *reinterpret_cast<const short8*>(Bp + r16 + kk);
    };
    auto MM = [&](const KBufs& u) {
        acc[0][0] = __builtin_amdgcn_mfma_f32_16x16x32_bf16(u.a0, u.b0, acc[0][0], 0, 0, 0);
        acc[0][1] = __builtin_amdgcn_mfma_f32_16x16x32_bf16(u.a0, u.b1, acc[0][1], 0, 0, 0);
        acc[1][0] = __builtin_amdgcn_mfma_f32_16x16x32_bf16(u.a1, u.b0, acc[1][0], 0, 0, 0);
        acc[1][1] = __builtin_amdgcn_mfma_f32_16x16x32_bf16(u.a1, u.b1, acc[1][1], 0, 0, 0);
    };
    LD(u0, 0); LD(u1, 32); LD(u2, 64);
    for (int k = 0; k < KL; k += 128) {
        LD(u3, k + 96);  MM(u0);
        LD(u0, k + 128); MM(u1);
        LD(u1, k + 160); MM(u2);
        LD(u2, k + 192); MM(u3);
    }
    #pragma unroll
    for (int i = 0; i < 2; ++i)
        #pragma unroll
        for (int j = 0; j < 2; ++j) {
            int gcol = bn + wc * 32 + j * 16 + lr;
            #pragma unroll
            for (int r = 0; r < 4; ++r) {
                int grow = bm + wr * 32 + i * 16 + lk * 4 + r;
                C[(size_t)grow * N + gcol] = acc[i][j][r];
            }
        }
}

// ---------------- sparse ops ----------------
__global__ __launch_bounds__(256) void neiagg_kernel(
    const float* __restrict__ nei0, const float* __restrict__ nei1,
    const unsigned short* __restrict__ hn0, const unsigned short* __restrict__ hn1,
    unsigned short* __restrict__ hagg) {
    const int row = blockIdx.x, br = blockIdx.y, t = threadIdx.x;
    const float* nei = br ? nei1 : nei0;
    const unsigned short* hn = br ? hn1 : hn0;
    __shared__ int idxs[256];
    __shared__ int cnt;
    if (t == 0) cnt = 0;
    __syncthreads();
    const float4* nr = reinterpret_cast<const float4*>(nei + (size_t)row * 4096);
    for (int j = t; j < 1024; j += 256) {
        float4 v = nr[j];
        if (v.x != 0.f) { int s = atomicAdd(&cnt, 1); if (s < 256) idxs[s] = j * 4 + 0; }
        if (v.y != 0.f) { int s = atomicAdd(&cnt, 1); if (s < 256) idxs[s] = j * 4 + 1; }
        if (v.z != 0.f) { int s = atomicAdd(&cnt, 1); if (s < 256) idxs[s] = j * 4 + 2; }
        if (v.w != 0.f) { int s = atomicAdd(&cnt, 1); if (s < 256) idxs[s] = j * 4 + 3; }
    }
    __syncthreads();
    int n = cnt < 256 ? cnt : 256;
    float inv = frcp(fmaxf((float)cnt, 1.f));
    int c = t * 2;
    float a0 = 0.f, a1 = 0.f, b0 = 0.f, b1 = 0.f;
    int k = 0;
    for (; k + 2 <= n; k += 2) {
        ushort2 u = *reinterpret_cast<const ushort2*>(&hn[(size_t)idxs[k] * 512 + c]);
        ushort2 v = *reinterpret_cast<const ushort2*>(&hn[(size_t)idxs[k + 1] * 512 + c]);
        a0 += bf2f(u.x); a1 += bf2f(u.y);
        b0 += bf2f(v.x); b1 += bf2f(v.y);
    }
    if (k < n) {
        ushort2 u = *reinterpret_cast<const ushort2*>(&hn[(size_t)idxs[k] * 512 + c]);
        a0 += bf2f(u.x); a1 += bf2f(u.y);
    }
    ushort2 o; o.x = f2bf((a0 + b0) * inv); o.y = f2bf((a1 + b1) * inv);
    *reinterpret_cast<ushort2*>(&hagg[((size_t)br * 1024 + row) * 512 + c]) = o;
}

// views/masks; h_tar/h_mask bf16; tbuf has 2 split-K planes (stride PL)
__global__ void addelu_kernel(const unsigned short* __restrict__ ht,
                              const unsigned short* __restrict__ hm,
                              const float* __restrict__ tt, unsigned short* __restrict__ xcat,
                              int nh, int PL) {
    int idx = blockIdx.x * 256 + threadIdx.x;
    if (idx < nh) {
        float h1 = bf2f(ht[idx]), h2 = bf2f(hm[idx]);
        float t0 = tt[idx] + tt[idx + PL];
        float t1 = tt[idx + nh] + tt[idx + nh + PL];
        float a = h1 + t0, b = h2 + t0, c = h1 + t1, d = h2 + t1;
        xcat[(size_t)1 * nh + idx] = f2bf(a > 0.f ? a : fexp(a) - 1.f);
        xcat[(size_t)2 * nh + idx] = f2bf(b > 0.f ? b : fexp(b) - 1.f);
        xcat[(size_t)3 * nh + idx] = f2bf(c > 0.f ? c : fexp(c) - 1.f);
        xcat[(size_t)4 * nh + idx] = f2bf(d > 0.f ? d : fexp(d) - 1.f);
    }
}

// h1cat[br] = bf16(relu(adj_br @ (X0+X1)[br] + b1)); X has 2 split-K planes stride PL
__global__ __launch_bounds__(256) void spmm1_kernel(
    const int* __restrict__ cnts, const int* __restrict__ idxs, const float* __restrict__ wts,
    const float* __restrict__ X, int PL, const float* __restrict__ bias,
    unsigned short* __restrict__ out) {
    const int row = blockIdx.x * 4 + (threadIdx.x >> 6);
    const int br = blockIdx.y, t = threadIdx.x & 63;
    size_t base = ((size_t)br * 1024 + row) * 128;
    int n = cnts[br * 1024 + row];
    const float* Xb = X + (size_t)br * 1024 * 64;
    const float* Xb2 = Xb + PL;
    float acc = bias[t], a1 = 0.f;
    int k = 0;
    for (; k + 2 <= n; k += 2) {
        int   i0 = idxs[base + k], i1 = idxs[base + k + 1];
        float w0 = wts[base + k],  w1 = wts[base + k + 1];
        acc += w0 * (Xb[(size_t)i0 * 64 + t] + Xb2[(size_t)i0 * 64 + t]);
        a1  += w1 * (Xb[(size_t)i1 * 64 + t] + Xb2[(size_t)i1 * 64 + t]);
    }
    if (k < n) {
        int i0 = idxs[base + k];
        acc += wts[base + k] * (Xb[(size_t)i0 * 64 + t] + Xb2[(size_t)i0 * 64 + t]);
    }
    acc += a1;
    out[((size_t)br * 1024 + row) * 64 + t] = f2bf(fmaxf(acc, 0.f));
}

// Fused: g = adj_br @ h1 (gather bf16), o = g @ w2 + b2; br0 -> zcf_bf;
// br1..4 -> l2norm(o) -> hs + att row value.
__global__ __launch_bounds__(256) void spmm2_kernel(
    const int* __restrict__ cnts, const int* __restrict__ idxs, const float* __restrict__ wts,
    const unsigned short* __restrict__ H1, const float* __restrict__ w2,
    const float* __restrict__ b2, unsigned short* __restrict__ zcf_bf,
    float* __restrict__ hs, const float* __restrict__ att_w,
    const float* __restrict__ att_b, const float* __restrict__ att_vec,
    float* __restrict__ att_row) {
    const int wv = threadIdx.x >> 6;
    const int row = blockIdx.x * 4 + wv;
    const int br = blockIdx.y, t = threadIdx.x & 63;
    size_t base = ((size_t)br * 1024 + row) * 128;
    int n = cnts[br * 1024 + row];
    const unsigned short* Hb = H1 + (size_t)br * 1024 * 64;
    float g0 = 0.f, g1 = 0.f, g2 = 0.f, g3 = 0.f;
    int k = 0;
    for (; k + 4 <= n; k += 4) {
        g0 += wts[base + k]     * bf2f(Hb[(size_t)idxs[base + k]     * 64 + t]);
        g1 += wts[base + k + 1] * bf2f(Hb[(size_t)idxs[base + k + 1] * 64 + t]);
        g2 += wts[base + k + 2] * bf2f(Hb[(size_t)idxs[base + k + 2] * 64 + t]);
        g3 += wts[base + k + 3] * bf2f(Hb[(size_t)idxs[base + k + 3] * 64 + t]);
    }
    for (; k < n; ++k) g0 += wts[base + k] * bf2f(Hb[(size_t)idxs[base + k] * 64 + t]);
    float g = (g0 + g1) + (g2 + g3);
    __shared__ float rs[4][64];
    rs[wv][t] = g;   // same-wave write/read: lockstep, no barrier
    float o = b2[t];
    #pragma unroll
    for (int c = 0; c < 64; ++c) o += rs[wv][c] * w2[c * 64 + t];
    if (br == 0) {
        zcf_bf[(size_t)row * 64 + t] = f2bf(o);
        return;
    }
    float s = o * o;
    #pragma unroll
    for (int q = 32; q; q >>= 1) s += __shfl_down(s, q);
    s = __shfl(s, 0);
    float v = o * frcp(fmaxf(sqrtf(s), 1e-12f));
    hs[((size_t)(br - 1) * 1024 + row) * 64 + t] = v;
    rs[wv][t] = v;   // safe overwrite (wave-sync)
    float sa = att_b[t];
    #pragma unroll
    for (int c = 0; c < 64; ++c) sa += rs[wv][c] * att_w[c * 64 + t];
    float val = ftanh(sa) * att_vec[t];
    #pragma unroll
    for (int q = 32; q; q >>= 1) val += __shfl_down(val, q);
    if (t == 0) att_row[(size_t)(br - 1) * 1024 + row] = val;
}

__global__ __launch_bounds__(256) void attreduce_kernel(const float* __restrict__ att_row,
                                                        float* __restrict__ small) {
    const int v = blockIdx.x, t = threadIdx.x;
    const float* p = att_row + (size_t)v * 1024;
    float s = p[t] + p[t + 256] + p[t + 512] + p[t + 768];
    #pragma unroll
    for (int o = 32; o; o >>= 1) s += __shfl_down(s, o);
    __shared__ float ps[4];
    if ((t & 63) == 0) ps[t >> 6] = s;
    __syncthreads();
    if (t == 0) small[v] = ps[0] + ps[1] + ps[2] + ps[3];
}

// Fused projection head: rows [0,N) z_coarse (from zcf_bf), rows [N,2N) z_fine
__global__ __launch_bounds__(256) void projhead_kernel(
    const unsigned short* __restrict__ zcf_bf, const float* __restrict__ hs,
    const float* __restrict__ small, const float* __restrict__ proj_w,
    const float* __restrict__ proj_b, const float* __restrict__ mlp1_w,
    float* __restrict__ zcat, float* __restrict__ AC1) {
    const int wv = threadIdx.x >> 6;
    const int row = blockIdx.x * 4 + wv;
    const int t = threadIdx.x & 63;
    float zv;
    if (row < 1024) {
        zv = bf2f(zcf_bf[(size_t)row * 64 + t]);
    } else {
        int r = row - 1024;
        float e0 = small[0] * (1.f / 1024.f), e1 = small[1] * (1.f / 1024.f);
        float e2 = small[2] * (1.f / 1024.f), e3 = small[3] * (1.f / 1024.f);
        float mx = fmaxf(fmaxf(e0, e1), fmaxf(e2, e3));
        float x0 = expf(e0 - mx), x1 = expf(e1 - mx), x2 = expf(e2 - mx), x3 = expf(e3 - mx);
        float inv = 1.f / (x0 + x1 + x2 + x3);
        size_t ix = (size_t)r * 64 + t;
        zv = (x0 * hs[ix] + x1 * hs[ix + 65536] +
              x2 * hs[ix + 131072] + x3 * hs[ix + 196608]) * inv;
    }
    __shared__ float rs[4][64];
    rs[wv][t] = zv;
    float p = proj_b[t];
    #pragma unroll
    for (int c = 0; c < 64; ++c) p += rs[wv][c] * proj_w[c * 64 + t];
    p = ftanh(p);
    float s = p * p;
    #pragma unroll
    for (int q = 32; q; q >>= 1) s += __shfl_down(s, q);
    s = __shfl(s, 0);
    float r = p * frcp(fmaxf(sqrtf(s), 1e-12f));
    zcat[(size_t)row * 64 + t] = r;
    rs[wv][t] = r;
    if (t < 16) {
        float a = 0.f;
        #pragma unroll
        for (int c = 0; c < 64; ++c) a += rs[wv][c] * mlp1_w[c * 16 + t];
        AC1[(size_t)row * 16 + t] = a;
    }
}

// 4 anchors per block; per-block partial written to loss_part[bid] (no atomics/memset)
__global__ __launch_bounds__(256) void infonce_kernel(
    const float* __restrict__ zf, const float* __restrict__ zc,
    const float* __restrict__ A1, const float* __restrict__ C1,
    const float* __restrict__ b1, const float* __restrict__ m2,
    const float* __restrict__ b2v, float* __restrict__ loss_part) {
    const int i0 = blockIdx.x * 4, t = threadIdx.x;
    __shared__ __align__(16) float zfs[4][64];
    __shared__ float a1b[4][16], m2s[16];
    __shared__ float diag[4];
    __shared__ float wsum[4][4];
    if (t < 64) {
        #pragma unroll
        for (int ii = 0; ii < 4; ++ii) zfs[ii][t] = zf[(size_t)(i0 + ii) * 64 + t];
    }
    if (t < 16) {
        float bb = b1[t];
        #pragma unroll
        for (int ii = 0; ii < 4; ++ii) a1b[ii][t] = A1[(size_t)(i0 + ii) * 16 + t] + bb;
        m2s[t] = m2[t];
    }
    __syncthreads();
    const float b2 = b2v[0];
    float acc[4] = {};
    for (int j = t; j < 1024; j += 256) {
        const float4* zcj = reinterpret_cast<const float4*>(zc + (size_t)j * 64);
        float dot[4] = {};
        #pragma unroll
        for (int e = 0; e < 16; ++e) {
            float4 b = zcj[e];
            #pragma unroll
            for (int ii = 0; ii < 4; ++ii) {
                float4 a = reinterpret_cast<const float4*>(zfs[ii])[e];
                dot[ii] += a.x * b.x + a.y * b.y + a.z * b.z + a.w * b.w;
            }
        }
        float c1j[16];
        #pragma unroll
        for (int q = 0; q < 4; ++q) {
            float4 c4 = reinterpret_cast<const float4*>(C1 + (size_t)j * 16)[q];
            c1j[q * 4 + 0] = c4.x; c1j[q * 4 + 1] = c4.y;
            c1j[q * 4 + 2] = c4.z; c1j[q * 4 + 3] = c4.w;
        }
        #pragma unroll
        for (int ii = 0; ii < 4; ++ii) {
            float logit = dot[ii] * 2.0f; // 1/TAU
            float h = b2;
            #pragma unroll
            for (int k = 0; k < 16; ++k) h += ftanh(a1b[ii][k] + c1j[k]) * m2s[k];
            acc[ii] += fexp(logit) * fsigmoid(h);
            if (j == i0 + ii) diag[ii] = logit;
        }
    }
    #pragma unroll
    for (int ii = 0; ii < 4; ++ii) {
        float a = acc[ii];
        #pragma unroll
        for (int o = 32; o; o >>= 1) a += __shfl_down(a, o);
        if ((t & 63) == 0) wsum[t >> 6][ii] = a;
    }
    __syncthreads();
    if (t == 0) {
        float part = 0.f;
        #pragma unroll
        for (int ii = 0; ii < 4; ++ii) {
            float denom = wsum[0][ii] + wsum[1][ii] + wsum[2][ii] + wsum[3][ii];
            part += logf(denom) - diag[ii];
        }
        loss_part[blockIdx.x] = part;
    }
}

// sum 256 per-block partials -> loss / 1024
__global__ __launch_bounds__(256) void finalize_kernel(const float* __restrict__ loss_part,
                                                       float* __restrict__ out) {
    const int t = threadIdx.x;
    float s = loss_part[t];
    #pragma unroll
    for (int o = 32; o; o >>= 1) s += __shfl_down(s, o);
    __shared__ float ps[4];
    if ((t & 63) == 0) ps[t >> 6] = s;
    __syncthreads();
    if (t == 0) out[0] = (ps[0] + ps[1] + ps[2] + ps[3]) * (1.f / 1024.f);
}

extern "C" void kernel_launch(void* const* d_in, const int* in_sizes, int n_in,
                              void* d_out, int out_size, void* d_ws, size_t ws_size,
                              hipStream_t stream) {
    const float* feat0     = (const float*)d_in[0];
    const float* feat1     = (const float*)d_in[1];
    const float* feat2     = (const float*)d_in[2];
    const float* mask_feat = (const float*)d_in[3];
    const float* nei0      = (const float*)d_in[4];
    const float* nei1      = (const float*)d_in[5];
    const float* adj0      = (const float*)d_in[6];
    const float* adj1      = (const float*)d_in[7];
    const float* madj0     = (const float*)d_in[8];
    const float* madj1     = (const float*)d_in[9];
    const float* fc0_w = (const float*)d_in[10];
    const float* fc0_b = (const float*)d_in[11];
    const float* fc1_w = (const float*)d_in[12];
    const float* fc1_b = (const float*)d_in[13];
    const float* fc2_w = (const float*)d_in[14];
    const float* fc2_b = (const float*)d_in[15];
    const float* agg0_w = (const float*)d_in[16];
    const float* agg1_w = (const float*)d_in[17];
    const float* gcn_w1 = (const float*)d_in[18];
    const float* gcn_b1 = (const float*)d_in[19];
    const float* gcn_w2 = (const float*)d_in[20];
    const float* gcn_b2 = (const float*)d_in[21];
    const float* att_w  = (const float*)d_in[22];
    const float* att_b  = (const float*)d_in[23];
    const float* att_vec = (const float*)d_in[24];
    const float* proj_w = (const float*)d_in[25];
    const float* proj_b = (const float*)d_in[26];
    const float* mlp1_w = (const float*)d_in[27];
    const float* mlp1_b = (const float*)d_in[28];
    const float* mlp2_w = (const float*)d_in[29];
    const float* mlp2_b = (const float*)d_in[30];

    const int N = 1024, M = 4096, D0 = 1024, D1 = 512, H = 512, E = 64;
    typedef unsigned short bf;

    // ---- workspace ----
    float* W = (float*)d_ws;
    size_t off = 0;
    auto allocf = [&](size_t n) { float* p = W + off; off += n; return p; };
    float* tbuf    = allocf((size_t)2 * 2 * N * H); // 2 split-K planes
    float* xw1cat  = allocf((size_t)2 * 5 * N * E); // 2 split-K planes
    float* hs      = allocf((size_t)4 * N * E);
    float* zcat    = allocf((size_t)2 * N * E);
    float* AC1     = allocf((size_t)2 * N * 16);
    float* att_row = allocf((size_t)4 * N);
    float* small   = allocf(16);
    float* loss_part = allocf(256);
    float* adj_wts = allocf((size_t)5 * 1024 * 128);
    int*   adj_idx = (int*)allocf((size_t)5 * 1024 * 128);
    int*   adj_cnt = (int*)allocf((size_t)5 * 1024);
    bf* BP = (bf*)(W + off);
    size_t boff = 0;
    auto allocb = [&](size_t n) { bf* p = BP + boff; boff += n; return p; };
    bf* feat0_bf = allocb((size_t)N * D0);   // feat0 | mask contiguous
    bf* mask_bf  = allocb((size_t)N * D0);
    bf* feat1_bf = allocb((size_t)M * D1);   // feat1 | feat2 contiguous
    bf* feat2_bf = allocb((size_t)M * D1);
    bf* xcat_bf  = allocb((size_t)5 * N * H); // branch0 = h_tar bf16
    bf* hmask_bf = allocb((size_t)N * H);
    bf* hnei0_bf = allocb((size_t)M * H);    // hnei0 | hnei1 contiguous
    bf* hnei1_bf = allocb((size_t)M * H);
    bf* hagg_bf  = allocb((size_t)2 * N * H);
    bf* h1cat_bf = allocb((size_t)5 * N * E);
    bf* zcf_bf   = allocb((size_t)N * E);
    bf* fc0_wT  = allocb((size_t)H * D0);
    bf* fc1_wT  = allocb((size_t)H * D1);
    bf* fc2_wT  = allocb((size_t)H * D1);
    bf* agg0_wT = allocb((size_t)H * H);
    bf* agg1_wT = allocb((size_t)H * H);
    bf* gw1_T   = allocb((size_t)E * H);

    // single merged prep launch: 6 weight transposes + 4 input casts + adjprep
    {
        CastArr a; int tile = 0, i = 0;
        auto addT = [&](const float* in, bf* out, int R, int C) {
            int tc = (C + 31) / 32, trn = (R + 31) / 32;
            a.t[i++] = CTDesc{in, out, R, C, tc, tile};
            tile += tc * trn;
        };
        addT(fc0_w, fc0_wT, D0, H);
        addT(fc1_w, fc1_wT, D1, H);
        addT(fc2_w, fc2_wT, D1, H);
        addT(agg0_w, agg0_wT, H, H);
        addT(agg1_w, agg1_wT, H, H);
        addT(gcn_w1, gw1_T, H, E);
        a.nt = i; a.T = tile;
        int s4 = 0, fi = 0;
        auto addF = [&](const float* in, bf* out, int n) {
            a.f[fi++] = CMDesc{in, out, s4}; s4 += n / 4;
        };
        addF(feat0, feat0_bf, N * D0);
        addF(mask_feat, mask_bf, N * D0);
        addF(feat1, feat1_bf, M * D1);
        addF(feat2, feat2_bf, M * D1);
        a.nf = fi; a.total4 = s4; a.F = (s4 + 255) / 256;
        a.adj0 = adj0; a.adj1 = adj1; a.madj0 = madj0; a.madj1 = madj1;
        a.cnts = adj_cnt; a.idxs = adj_idx; a.wts = adj_wts;
        int nb = a.T + a.F + (5 * 1024) / 4;
        cast_all_kernel<<<nb, 256, 0, stream>>>(a);
    }

    // merged projections GEMM (64x64 LDS-staged): seg0 [feat0;mask]@fc0 -> [xcat0|hmask],
    // seg1 [feat1;feat2]@fc1/fc2 -> hnei. grid (8, 32+128) = 1280 blocks, XCD-striped.
    {
        GArr g;
        g.s[0] = GSeg{feat0_bf, fc0_wT, nullptr, fc0_b, nullptr,
                      xcat_bf, hmask_bf, N, 1 << 30, D0, ACT_ELU, 0};
        g.s[1] = GSeg{feat1_bf, fc1_wT, fc2_wT, fc1_b, fc2_b,
                      hnei0_bf, nullptr, 2 * M, M, D1, ACT_ELU, 32};
        g.ns = 2; g.N = H;
        gemm_seg_kernel<<<dim3(H / 64, 32 + 128), 256, 0, stream>>>(g);
    }

    // meta-path aggregation
    neiagg_kernel<<<dim3(N, 2), 256, 0, stream>>>(nei0, nei1, hnei0_bf, hnei1_bf, hagg_bf);
    // agg GEMM split-K x2: [hagg0;hagg1]@agg0/agg1 -> 2 fp32 planes in tbuf
    gemm_splitk_kernel<<<dim3(H / 64, 2 * N / 64, 2), 256, 0, stream>>>(
        hagg_bf, agg0_wT, agg1_wT, N, tbuf, 2 * N, H, H, 256);
    addelu_kernel<<<(N * H + 255) / 256, 256, 0, stream>>>(xcat_bf, hmask_bf, tbuf, xcat_bf,
                                                           N * H, 2 * N * H);

    // GCN layer 1: xcat@gw1 split-K x2 -> 2 planes, then spmm1 (sums planes)
    gemm_splitk_kernel<<<dim3(1, 5 * N / 64, 2), 256, 0, stream>>>(
        xcat_bf, gw1_T, nullptr, 1 << 30, xw1cat, 5 * N, H, E, 256);
    spmm1_kernel<<<dim3(N / 4, 5), 256, 0, stream>>>(adj_cnt, adj_idx, adj_wts,
                                                     xw1cat, 5 * N * E, gcn_b1, h1cat_bf);
    // GCN layer 2 fused: spmm2 = gather(h1) @ w2 + b2 (+l2norm +att)
    spmm2_kernel<<<dim3(N / 4, 5), 256, 0, stream>>>(adj_cnt, adj_idx, adj_wts, h1cat_bf,
                                                     gcn_w2, gcn_b2, zcf_bf, hs,
                                                     att_w, att_b, att_vec, att_row);
    attreduce_kernel<<<4, 256, 0, stream>>>(att_row, small);

    // fused zfine + projection + l2norm + mlp1 matvec
    projhead_kernel<<<2 * N / 4, 256, 0, stream>>>(zcf_bf, hs, small, proj_w, proj_b,
                                                   mlp1_w, zcat, AC1);

    // InfoNCE
    const float* zc = zcat;
    const float* zf = zcat + (size_t)N * E;
    const float* C1 = AC1;
    const float* A1 = AC1 + (size_t)N * 16;
    infonce_kernel<<<N / 4, 256, 0, stream>>>(zf, zc, A1, C1, mlp1_b, mlp2_w, mlp2_b, loss_part);

    finalize_kernel<<<1, 256, 0, stream>>>(loss_part, (float*)d_out);
}